// Round 5
// baseline (646.318 us; speedup 1.0000x reference)
//
#include <hip/hip_runtime.h>
#include <cmath>

// FAGCN: N=50000, E=1.6M, FEAT=512, HIDDEN=128, CLASS=40, 4 layers, eps=0.3
// R14: CSR build rewritten with global atomics — k_deg (atomicAdd deg) +
// scans + k_fill (atomic cursor scatter). Deletes k_hist/k_hscan/k_csr_fill
// (each 256 blocks = 12.5% occupancy, 2x 12.8MB 'partial' round-trip, 98
// PITCH-loop iters/block) and the partial/lrank buffers. Edge order within a
// CSR row becomes hw-determined: only perturbs f32 sum order (rounding noise
// << bf16 quant error). dis computed in k_scan3; cur aliases dead deg buffer.
// R13 counters: aggregate 62.7us/layer = hbm_bytes/bw (structural, random
// gather); the ~200us CSR build was the largest unattributed block.

#define HIDDEN 128
#define FEAT 512
#define NCLASS 40
#define LDST 40    // GEMM LDS row stride in ushorts (80 B)
#define LDSW 132   // k_out ws row stride in floats (528 B -> 4-bank shift/row)
#define BM1 64     // k_gemm1 M-tile

typedef __attribute__((ext_vector_type(8))) short short8;
typedef __attribute__((ext_vector_type(4))) float f32x4;

__device__ __forceinline__ float bf_lo(unsigned u) { return __uint_as_float(u << 16); }
__device__ __forceinline__ float bf_hi(unsigned u) { return __uint_as_float(u & 0xffff0000u); }
__device__ __forceinline__ unsigned pack_bf16(float x, float y) {
    unsigned ux = __float_as_uint(x);
    unsigned uy = __float_as_uint(y);
    unsigned lx = (ux + 0x7fffu + ((ux >> 16) & 1u)) >> 16;
    unsigned hy = (uy + 0x7fffu + ((uy >> 16) & 1u)) & 0xffff0000u;
    return hy | lx;
}
__device__ __forceinline__ float fast_tanh(float x) {
    x = fminf(fmaxf(x, -15.f), 15.f);
    float e = __expf(2.f * x);
    return (e - 1.f) / (e + 1.f);
}

// ---------------- degree histogram: edge-parallel global atomics ---------------
__global__ __launch_bounds__(256) void k_deg(const int* __restrict__ ei, int E,
                                             int* __restrict__ deg) {
    int e = blockIdx.x * 256 + threadIdx.x;
    if (e < E) atomicAdd(&deg[ei[E + e]], 1);
}

// ---------------- exclusive scan over node degrees (offs) ----------------
__global__ __launch_bounds__(256) void k_scan1(const int* __restrict__ deg, int* __restrict__ offs,
                                               int* __restrict__ part, int n) {
    __shared__ int s[256];
    int tid = threadIdx.x;
    int gid = blockIdx.x * 256 + tid;
    int v = (gid < n) ? deg[gid] : 0;
    s[tid] = v;
    __syncthreads();
    for (int off = 1; off < 256; off <<= 1) {
        int t = (tid >= off) ? s[tid - off] : 0;
        __syncthreads();
        s[tid] += t;
        __syncthreads();
    }
    if (gid < n) offs[gid] = s[tid] - v;
    if (tid == 255) part[blockIdx.x] = s[255];
}

__global__ __launch_bounds__(256) void k_scan2(int* __restrict__ part, int nb) {
    __shared__ int s[256];
    int tid = threadIdx.x;
    int v = (tid < nb) ? part[tid] : 0;
    s[tid] = v;
    __syncthreads();
    for (int off = 1; off < 256; off <<= 1) {
        int t = (tid >= off) ? s[tid - off] : 0;
        __syncthreads();
        s[tid] += t;
        __syncthreads();
    }
    if (tid < nb) part[tid] = s[tid] - v;
}

// scan3: finalize offs, init fill cursor (cur aliases deg: read deg first),
// compute dis = rsqrt(deg+1).
__global__ __launch_bounds__(256) void k_scan3(int* __restrict__ offs, const int* __restrict__ part,
                                               int* __restrict__ cur, float* __restrict__ dis,
                                               int n, int E) {
    int gid = blockIdx.x * 256 + threadIdx.x;
    if (gid < n) {
        int d = cur[gid];               // cur aliases deg; read degree first
        int o = offs[gid] + part[blockIdx.x];
        offs[gid] = o;
        cur[gid] = o;
        dis[gid] = rsqrtf((float)(d + 1));
    }
    if (gid == 0) offs[n] = E;
}

// ---------------- CSR fill: atomic cursor scatter ------------------------------
__global__ __launch_bounds__(256) void k_fill(const int* __restrict__ ei, int E,
                                              int* __restrict__ cur, int* __restrict__ csrc) {
    int e = blockIdx.x * 256 + threadIdx.x;
    if (e < E) {
        int dst = ei[E + e];
        int src = ei[e];
        int pos = atomicAdd(&cur[dst], 1);
        csrc[pos] = src;
    }
}

// ---------------- GEMM1: h = relu(x @ W1^T + b1), MFMA bf16 -------------------
__global__ __launch_bounds__(256) void k_gemm1(const float* __restrict__ x,
                                               const float* __restrict__ W1,
                                               const float* __restrict__ b1,
                                               float* __restrict__ h, int M) {
    __shared__ ushort As[BM1 * LDST];
    __shared__ ushort Bs[128 * LDST];
    const int tid = threadIdx.x;
    const int bm = blockIdx.x * BM1;
    const int wave = tid >> 6, lane = tid & 63;
    const int rh = (wave >> 1) * 32;   // wave row offset: 0 / 32
    const int ch = (wave & 1) * 64;    // wave col offset: 0 / 64
    const int sub = lane & 15, quad = lane >> 4;
    const int lrow = tid >> 3;         // 0..31
    const int lcol = (tid & 7) * 4;    // 0..28
    f32x4 acc[2][4] = {};
    float4 av[2], bv[4];
    // prologue: load K-tile 0 into registers
#pragma unroll
    for (int i = 0; i < 2; ++i) {
        int grow = bm + lrow + 32 * i;
        av[i] = (grow < M) ? *(const float4*)(x + (size_t)grow * FEAT + lcol)
                           : make_float4(0.f, 0.f, 0.f, 0.f);
    }
#pragma unroll
    for (int i = 0; i < 4; ++i)
        bv[i] = *(const float4*)(W1 + (size_t)(lrow + 32 * i) * FEAT + lcol);

    for (int k0 = 0; k0 < FEAT; k0 += 32) {
        // stage current tile regs -> LDS (bf16 pack)
#pragma unroll
        for (int i = 0; i < 2; ++i)
            *(uint2*)(As + (lrow + 32 * i) * LDST + lcol) =
                make_uint2(pack_bf16(av[i].x, av[i].y), pack_bf16(av[i].z, av[i].w));
#pragma unroll
        for (int i = 0; i < 4; ++i)
            *(uint2*)(Bs + (lrow + 32 * i) * LDST + lcol) =
                make_uint2(pack_bf16(bv[i].x, bv[i].y), pack_bf16(bv[i].z, bv[i].w));
        __syncthreads();
        // prefetch next K-tile into registers (overlaps ds_read + MFMA below)
        if (k0 + 32 < FEAT) {
            const int kn = k0 + 32;
#pragma unroll
            for (int i = 0; i < 2; ++i) {
                int grow = bm + lrow + 32 * i;
                av[i] = (grow < M) ? *(const float4*)(x + (size_t)grow * FEAT + kn + lcol)
                                   : make_float4(0.f, 0.f, 0.f, 0.f);
            }
#pragma unroll
            for (int i = 0; i < 4; ++i)
                bv[i] = *(const float4*)(W1 + (size_t)(lrow + 32 * i) * FEAT + kn + lcol);
        }
        short8 af[2], bfr[4];
#pragma unroll
        for (int t = 0; t < 2; ++t)
            af[t] = *(const short8*)(As + (rh + t * 16 + sub) * LDST + quad * 8);
#pragma unroll
        for (int u = 0; u < 4; ++u)
            bfr[u] = *(const short8*)(Bs + (ch + u * 16 + sub) * LDST + quad * 8);
#pragma unroll
        for (int t = 0; t < 2; ++t)
#pragma unroll
            for (int u = 0; u < 4; ++u)
                acc[t][u] = __builtin_amdgcn_mfma_f32_16x16x32_bf16(af[t], bfr[u], acc[t][u], 0, 0, 0);
        __syncthreads();
    }
    float b1v[4];
#pragma unroll
    for (int u = 0; u < 4; ++u) b1v[u] = b1[ch + u * 16 + sub];
#pragma unroll
    for (int t = 0; t < 2; ++t) {
#pragma unroll
        for (int u = 0; u < 4; ++u) {
            int col = ch + u * 16 + sub;
#pragma unroll
            for (int r2 = 0; r2 < 4; ++r2) {
                int grow = bm + rh + t * 16 + quad * 4 + r2;
                if (grow < M)
                    h[(size_t)grow * HIDDEN + col] = fmaxf(acc[t][u][r2] + b1v[u], 0.f);
            }
        }
    }
}

// ---------------- prep: bf16 pack + layer-0 dots -> {al,dis}, ar ----------------
__global__ __launch_bounds__(256) void k_prep(const float* __restrict__ h, unsigned* __restrict__ hbf,
                       const float* __restrict__ attl, const float* __restrict__ attr,
                       const float* __restrict__ dis, float2* __restrict__ al2,
                       float* __restrict__ ar, int n) {
    int node = (blockIdx.x * blockDim.x + threadIdx.x) >> 6;
    int lane = threadIdx.x & 63;
    if (node >= n) return;
    float2 hv = ((const float2*)(h + (size_t)node * HIDDEN))[lane];
    hbf[(size_t)node * 64 + lane] = pack_bf16(hv.x, hv.y);
    float pl = hv.x * attl[2 * lane] + hv.y * attl[2 * lane + 1];
    float pr = hv.x * attr[2 * lane] + hv.y * attr[2 * lane + 1];
    for (int off = 32; off; off >>= 1) {
        pl += __shfl_down(pl, off);
        pr += __shfl_down(pr, off);
    }
    if (lane == 0) {
        al2[node] = make_float2(pl, dis[node]);
        ar[node] = pr;
    }
}

// ---------------- aggregate: phase-1 coef batch (64/pass) + shfl distribution ---
__global__ __launch_bounds__(256) void k_aggregate(
                            const unsigned* __restrict__ hbf, const float* __restrict__ raw,
                            const float2* __restrict__ al2, const float* __restrict__ ar,
                            const int* __restrict__ offs, const int* __restrict__ csrc,
                            float* __restrict__ hout, unsigned* __restrict__ houtbf,
                            const float* __restrict__ attl_n, const float* __restrict__ attr_n,
                            float2* __restrict__ al2_o, float* __restrict__ ar_o, int n) {
    int node = (blockIdx.x * blockDim.x + threadIdx.x) >> 6;
    int lane = threadIdx.x & 63;
    if (node >= n) return;
    const int grp = lane >> 4;
    const int sub = lane & 15;
    const float arn = ar[node];
    const float2 selfld = al2[node];
    const float disn = selfld.y;
    float acc[8] = {0.f, 0.f, 0.f, 0.f, 0.f, 0.f, 0.f, 0.f};
    int e0 = offs[node], e1 = offs[node + 1];
    for (int base = e0; base < e1; base += 64) {
        int cnt = min(64, e1 - base);
        // phase 1: one coef per lane (zero-padded past cnt)
        int idx = base + lane;
        int smy = (lane < cnt) ? csrc[idx] : node;
        float2 lmy = al2[smy];
        float cmy = (lane < cnt) ? fast_tanh(lmy.x + arn) * lmy.y * disn : 0.f;
        // phase 2: 16-edge hot loop, src/coef via shfl
        int t = 0;
        for (; t + 16 <= cnt; t += 16) {
            int sa = __shfl(smy, t + grp);
            int sb = __shfl(smy, t + 4 + grp);
            int sc = __shfl(smy, t + 8 + grp);
            int sd = __shfl(smy, t + 12 + grp);
            float ca = __shfl(cmy, t + grp);
            float cb = __shfl(cmy, t + 4 + grp);
            float cc = __shfl(cmy, t + 8 + grp);
            float cd = __shfl(cmy, t + 12 + grp);
            uint4 ra = *(const uint4*)(hbf + (size_t)sa * 64 + sub * 4);
            uint4 rb = *(const uint4*)(hbf + (size_t)sb * 64 + sub * 4);
            uint4 rc = *(const uint4*)(hbf + (size_t)sc * 64 + sub * 4);
            uint4 rd = *(const uint4*)(hbf + (size_t)sd * 64 + sub * 4);
            acc[0] += ca * bf_lo(ra.x); acc[1] += ca * bf_hi(ra.x);
            acc[2] += ca * bf_lo(ra.y); acc[3] += ca * bf_hi(ra.y);
            acc[4] += ca * bf_lo(ra.z); acc[5] += ca * bf_hi(ra.z);
            acc[6] += ca * bf_lo(ra.w); acc[7] += ca * bf_hi(ra.w);
            acc[0] += cb * bf_lo(rb.x); acc[1] += cb * bf_hi(rb.x);
            acc[2] += cb * bf_lo(rb.y); acc[3] += cb * bf_hi(rb.y);
            acc[4] += cb * bf_lo(rb.z); acc[5] += cb * bf_hi(rb.z);
            acc[6] += cb * bf_lo(rb.w); acc[7] += cb * bf_hi(rb.w);
            acc[0] += cc * bf_lo(rc.x); acc[1] += cc * bf_hi(rc.x);
            acc[2] += cc * bf_lo(rc.y); acc[3] += cc * bf_hi(rc.y);
            acc[4] += cc * bf_lo(rc.z); acc[5] += cc * bf_hi(rc.z);
            acc[6] += cc * bf_lo(rc.w); acc[7] += cc * bf_hi(rc.w);
            acc[0] += cd * bf_lo(rd.x); acc[1] += cd * bf_hi(rd.x);
            acc[2] += cd * bf_lo(rd.y); acc[3] += cd * bf_hi(rd.y);
            acc[4] += cd * bf_lo(rd.z); acc[5] += cd * bf_hi(rd.z);
            acc[6] += cd * bf_lo(rd.w); acc[7] += cd * bf_hi(rd.w);
        }
        for (; t < cnt; t += 4) {   // zero-padded tail (covers 1-3 leftovers too)
            int sa = __shfl(smy, t + grp);
            float ca = __shfl(cmy, t + grp);
            uint4 ra = *(const uint4*)(hbf + (size_t)sa * 64 + sub * 4);
            acc[0] += ca * bf_lo(ra.x); acc[1] += ca * bf_hi(ra.x);
            acc[2] += ca * bf_lo(ra.y); acc[3] += ca * bf_hi(ra.y);
            acc[4] += ca * bf_lo(ra.z); acc[5] += ca * bf_hi(ra.z);
            acc[6] += ca * bf_lo(ra.w); acc[7] += ca * bf_hi(ra.w);
        }
    }
#pragma unroll
    for (int j = 0; j < 8; ++j) {
        acc[j] += __shfl_xor(acc[j], 16);
        acc[j] += __shfl_xor(acc[j], 32);
    }
    {   // self-loop term (post-reduce, replicated across groups)
        float c = fast_tanh(selfld.x + arn) * disn * disn;
        uint4 r = *(const uint4*)(hbf + (size_t)node * 64 + sub * 4);
        acc[0] += c * bf_lo(r.x); acc[1] += c * bf_hi(r.x);
        acc[2] += c * bf_lo(r.y); acc[3] += c * bf_hi(r.y);
        acc[4] += c * bf_lo(r.z); acc[5] += c * bf_hi(r.z);
        acc[6] += c * bf_lo(r.w); acc[7] += c * bf_hi(r.w);
    }
    float o[8];
    {
        float4 rv0 = *(const float4*)(raw + (size_t)node * HIDDEN + sub * 8);
        float4 rv1 = *(const float4*)(raw + (size_t)node * HIDDEN + sub * 8 + 4);
        o[0] = acc[0] + 0.3f * rv0.x; o[1] = acc[1] + 0.3f * rv0.y;
        o[2] = acc[2] + 0.3f * rv0.z; o[3] = acc[3] + 0.3f * rv0.w;
        o[4] = acc[4] + 0.3f * rv1.x; o[5] = acc[5] + 0.3f * rv1.y;
        o[6] = acc[6] + 0.3f * rv1.z; o[7] = acc[7] + 0.3f * rv1.w;
    }
    if (grp == 0) {
        *(float4*)(hout + (size_t)node * HIDDEN + sub * 8) = make_float4(o[0], o[1], o[2], o[3]);
        *(float4*)(hout + (size_t)node * HIDDEN + sub * 8 + 4) = make_float4(o[4], o[5], o[6], o[7]);
        if (houtbf) {
            uint4 pk = make_uint4(pack_bf16(o[0], o[1]), pack_bf16(o[2], o[3]),
                                  pack_bf16(o[4], o[5]), pack_bf16(o[6], o[7]));
            *(uint4*)(houtbf + (size_t)node * 64 + sub * 4) = pk;
        }
    }
    if (attl_n) {
        float4 a0 = *(const float4*)(attl_n + sub * 8);
        float4 a1 = *(const float4*)(attl_n + sub * 8 + 4);
        float4 c0 = *(const float4*)(attr_n + sub * 8);
        float4 c1 = *(const float4*)(attr_n + sub * 8 + 4);
        float pl = o[0] * a0.x + o[1] * a0.y + o[2] * a0.z + o[3] * a0.w +
                   o[4] * a1.x + o[5] * a1.y + o[6] * a1.z + o[7] * a1.w;
        float pr = o[0] * c0.x + o[1] * c0.y + o[2] * c0.z + o[3] * c0.w +
                   o[4] * c1.x + o[5] * c1.y + o[6] * c1.z + o[7] * c1.w;
        for (int off = 8; off; off >>= 1) {
            pl += __shfl_xor(pl, off);
            pr += __shfl_xor(pr, off);
        }
        if (lane == 0) {
            al2_o[node] = make_float2(pl, disn);
            ar_o[node] = pr;
        }
    }
}

// ---------------- output: log_softmax(h @ W2^T + b2) ---------------------------
__global__ __launch_bounds__(256, 4) void k_out(const float* __restrict__ h,
                                                const float* __restrict__ W2,
                                                const float* __restrict__ b2,
                                                float* __restrict__ out, int n) {
    __shared__ float ws[NCLASS * LDSW];
    __shared__ float bs[NCLASS];
    const int tid = threadIdx.x;
    for (int i = tid; i < NCLASS * (HIDDEN / 4); i += 256) {
        int r = i >> 5;          // row (class), 32 float4 per row
        int c4 = i & 31;         // float4 index within row
        *(float4*)(ws + r * LDSW + c4 * 4) = ((const float4*)W2)[i];
    }
    if (tid < NCLASS) bs[tid] = b2[tid];
    __syncthreads();
    int node = blockIdx.x * 32 + (tid >> 3);
    const int ol = tid & 7;
    if (node >= n) return;
    const float* hr = h + (size_t)node * HIDDEN;
    float acc[5];
#pragma unroll
    for (int c = 0; c < 5; ++c) acc[c] = bs[ol + 8 * c];
#pragma unroll
    for (int k0 = 0; k0 < HIDDEN; k0 += 16) {
        float4 h0 = *(const float4*)(hr + k0);
        float4 h1 = *(const float4*)(hr + k0 + 4);
        float4 h2v = *(const float4*)(hr + k0 + 8);
        float4 h3 = *(const float4*)(hr + k0 + 12);
#pragma unroll
        for (int c = 0; c < 5; ++c) {
            const float* w = ws + (ol + 8 * c) * LDSW + k0;
            float4 w0 = *(const float4*)(w);
            float4 w1 = *(const float4*)(w + 4);
            float4 w2v = *(const float4*)(w + 8);
            float4 w3 = *(const float4*)(w + 12);
            acc[c] += h0.x * w0.x + h0.y * w0.y + h0.z * w0.z + h0.w * w0.w +
                      h1.x * w1.x + h1.y * w1.y + h1.z * w1.z + h1.w * w1.w +
                      h2v.x * w2v.x + h2v.y * w2v.y + h2v.z * w2v.z + h2v.w * w2v.w +
                      h3.x * w3.x + h3.y * w3.y + h3.z * w3.z + h3.w * w3.w;
        }
    }
    float m = acc[0];
#pragma unroll
    for (int c = 1; c < 5; ++c) m = fmaxf(m, acc[c]);
    m = fmaxf(m, __shfl_xor(m, 1));
    m = fmaxf(m, __shfl_xor(m, 2));
    m = fmaxf(m, __shfl_xor(m, 4));
    float ssum = 0.f;
#pragma unroll
    for (int c = 0; c < 5; ++c) ssum += expf(acc[c] - m);
    ssum += __shfl_xor(ssum, 1);
    ssum += __shfl_xor(ssum, 2);
    ssum += __shfl_xor(ssum, 4);
    float lse = m + logf(ssum);
    float* orow = out + (size_t)node * NCLASS;
#pragma unroll
    for (int c = 0; c < 5; ++c) orow[ol + 8 * c] = acc[c] - lse;
}

extern "C" void kernel_launch(void* const* d_in, const int* in_sizes, int n_in,
                              void* d_out, int out_size, void* d_ws, size_t ws_size,
                              hipStream_t stream) {
    const float* x    = (const float*)d_in[0];
    const int*   ei   = (const int*)d_in[1];
    const float* W1   = (const float*)d_in[2];
    const float* b1   = (const float*)d_in[3];
    const float* W2   = (const float*)d_in[4];
    const float* b2   = (const float*)d_in[5];
    const float* attl = (const float*)d_in[6];
    const float* attr = (const float*)d_in[7];
    const int N = in_sizes[0] / FEAT;
    const int E = in_sizes[1] / 2;
    float* out = (float*)d_out;

    char* p = (char*)d_ws;
    auto take = [&](size_t bytes) {
        void* q = (void*)p;
        p += (bytes + 255) & ~(size_t)255;
        return q;
    };
    float*    h0   = (float*)take((size_t)N * HIDDEN * 4);  // = raw
    float*    h1   = (float*)take((size_t)N * HIDDEN * 4);
    float*    h2   = (float*)take((size_t)N * HIDDEN * 4);
    unsigned* hb0  = (unsigned*)take((size_t)N * 64 * 4);
    unsigned* hb1  = (unsigned*)take((size_t)N * 64 * 4);
    int*      deg  = (int*)take((size_t)N * 4);   // reused as fill cursor
    float*    dis  = (float*)take((size_t)N * 4);
    int*      offs = (int*)take((size_t)(N + 1) * 4);
    int*      csrc = (int*)take((size_t)E * 4);
    float2*   al2A = (float2*)take((size_t)N * 8);
    float2*   al2B = (float2*)take((size_t)N * 8);
    float*    arA  = (float*)take((size_t)N * 4);
    float*    arB  = (float*)take((size_t)N * 4);
    int*      part = (int*)take(1024);

    const int nbl = (N + 255) / 256;
    const int ebl = (E + 255) / 256;

    hipMemsetAsync(deg, 0, (size_t)N * 4, stream);
    k_deg<<<ebl, 256, 0, stream>>>(ei, E, deg);
    k_scan1<<<nbl, 256, 0, stream>>>(deg, offs, part, N);
    k_scan2<<<1, 256, 0, stream>>>(part, nbl);
    k_scan3<<<nbl, 256, 0, stream>>>(offs, part, deg, dis, N, E);  // cur = deg buffer
    k_fill<<<ebl, 256, 0, stream>>>(ei, E, deg, csrc);

    k_gemm1<<<(N + BM1 - 1) / BM1, 256, 0, stream>>>(x, W1, b1, h0, N);
    k_prep<<<(N + 3) / 4, 256, 0, stream>>>(h0, hb0, attl, attr, dis, al2A, arA, N);

    float*    fout[4] = {h1, h2, h1, h2};
    unsigned* hbin = hb0, *hbout = hb1;
    float2*   alin = al2A, *alout = al2B;
    float*    arin = arA,  *arout = arB;
    for (int l = 0; l < 4; ++l) {
        const float* attl_n = (l < 3) ? (attl + (l + 1) * HIDDEN) : nullptr;
        const float* attr_n = (l < 3) ? (attr + (l + 1) * HIDDEN) : nullptr;
        unsigned* hbo = (l < 3) ? hbout : nullptr;
        k_aggregate<<<(N + 3) / 4, 256, 0, stream>>>(hbin, h0, alin, arin, offs, csrc,
                                                     fout[l], hbo, attl_n, attr_n,
                                                     alout, arout, N);
        unsigned* tb = hbin; hbin = hbout; hbout = tb;
        float2* ta = alin; alin = alout; alout = ta;
        float* tr = arin; arin = arout; arout = tr;
    }

    k_out<<<(N + 31) / 32, 256, 0, stream>>>(h2, W2, b2, out, N);
}

// Round 6
// 522.990 us; speedup vs baseline: 1.2358x; 1.2358x over previous
//
#include <hip/hip_runtime.h>
#include <cmath>

// FAGCN: N=50000, E=1.6M, FEAT=512, HIDDEN=128, CLASS=40, 4 layers, eps=0.3
// R15: CSR build REVERTED to R13's LDS-histogram pipeline (k_hist/k_hscan/
// k_scan*/k_csr_fill). R14's atomic build was a measured regression: k_fill
// 133us — atomicAdd-with-return latency chain + 101MB line-granular writeback
// (VALU 0.35%, HBM 10%). One change on top of R13: k_aggregate phase-2 is
// 2-deep software-pipelined — next 16-edge block's 4 uint4 gathers issue
// before the current block's FMAs (8 gathers in flight/lane), VGPR kept <64
// (occupancy cliff). R13 agg counters: 62.6us, VALU 50%, occ 64%, fetch
// 180MB = 2.85 TB/s random-line — testing whether MLP or fabric is the limit.

#define HIDDEN 128
#define FEAT 512
#define NCLASS 40
#define LDST 40    // GEMM LDS row stride in ushorts (80 B)
#define LDSW 132   // k_out ws row stride in floats (528 B -> 4-bank shift/row)
#define NB 256     // histogram chunks (= blocks)
#define PITCH 12544  // words per partial row: 4 nodes/word -> supports N<=50176
#define BM1 64     // k_gemm1 M-tile

typedef __attribute__((ext_vector_type(8))) short short8;
typedef __attribute__((ext_vector_type(4))) float f32x4;

__device__ __forceinline__ float bf_lo(unsigned u) { return __uint_as_float(u << 16); }
__device__ __forceinline__ float bf_hi(unsigned u) { return __uint_as_float(u & 0xffff0000u); }
__device__ __forceinline__ unsigned pack_bf16(float x, float y) {
    unsigned ux = __float_as_uint(x);
    unsigned uy = __float_as_uint(y);
    unsigned lx = (ux + 0x7fffu + ((ux >> 16) & 1u)) >> 16;
    unsigned hy = (uy + 0x7fffu + ((uy >> 16) & 1u)) & 0xffff0000u;
    return hy | lx;
}
__device__ __forceinline__ float fast_tanh(float x) {
    x = fminf(fmaxf(x, -15.f), 15.f);
    float e = __expf(2.f * x);
    return (e - 1.f) / (e + 1.f);
}

#define ACC4(c, r) \
    acc[0] += c * bf_lo(r.x); acc[1] += c * bf_hi(r.x); \
    acc[2] += c * bf_lo(r.y); acc[3] += c * bf_hi(r.y); \
    acc[4] += c * bf_lo(r.z); acc[5] += c * bf_hi(r.z); \
    acc[6] += c * bf_lo(r.w); acc[7] += c * bf_hi(r.w);

// ---------------- per-chunk LDS histogram (8-bit packed) + local rank ----------
__global__ __launch_bounds__(256) void k_hist(const int* __restrict__ ei, int E, int CE,
                                              unsigned* __restrict__ partial,
                                              ushort* __restrict__ lrank) {
    __shared__ unsigned lh[PITCH];
    const int b = blockIdx.x, tid = threadIdx.x;
    for (int w = tid; w < PITCH; w += 256) lh[w] = 0;
    __syncthreads();
    int e0 = b * CE, e1 = min(E, e0 + CE);
    for (int e = e0 + tid; e < e1; e += 256) {
        int dst = ei[E + e];
        int sh = (dst & 3) * 8;
        unsigned old = atomicAdd(&lh[dst >> 2], 1u << sh);
        lrank[e] = (ushort)((old >> sh) & 0xffu);
    }
    __syncthreads();
    unsigned* prow = partial + (size_t)b * PITCH;
    for (int w = tid; w < PITCH; w += 256) prow[w] = lh[w];
}

// ---------------- cross-chunk exclusive scan (in place) + degree + dis ---------
__global__ __launch_bounds__(256) void k_hscan(unsigned* __restrict__ partial,
                                               int* __restrict__ deg,
                                               float* __restrict__ dis, int n) {
    int w = blockIdx.x * 256 + threadIdx.x;
    if (w >= PITCH) return;
    unsigned run = 0;
    size_t idx = w;
    for (int b = 0; b < NB; ++b, idx += PITCH) {
        unsigned v = partial[idx];
        partial[idx] = run;
        run += v;
    }
    int node = 4 * w;
    int d0 = run & 0xffu, d1 = (run >> 8) & 0xffu, d2 = (run >> 16) & 0xffu, d3 = run >> 24;
    if (node < n)     { deg[node]     = d0; dis[node]     = rsqrtf((float)(d0 + 1)); }
    if (node + 1 < n) { deg[node + 1] = d1; dis[node + 1] = rsqrtf((float)(d1 + 1)); }
    if (node + 2 < n) { deg[node + 2] = d2; dis[node + 2] = rsqrtf((float)(d2 + 1)); }
    if (node + 3 < n) { deg[node + 3] = d3; dis[node + 3] = rsqrtf((float)(d3 + 1)); }
}

// ---------------- exclusive scan over node degrees (offs) ----------------
__global__ __launch_bounds__(256) void k_scan1(const int* __restrict__ deg, int* __restrict__ offs,
                                               int* __restrict__ part, int n) {
    __shared__ int s[256];
    int tid = threadIdx.x;
    int gid = blockIdx.x * 256 + tid;
    int v = (gid < n) ? deg[gid] : 0;
    s[tid] = v;
    __syncthreads();
    for (int off = 1; off < 256; off <<= 1) {
        int t = (tid >= off) ? s[tid - off] : 0;
        __syncthreads();
        s[tid] += t;
        __syncthreads();
    }
    if (gid < n) offs[gid] = s[tid] - v;
    if (tid == 255) part[blockIdx.x] = s[255];
}

__global__ __launch_bounds__(256) void k_scan2(int* __restrict__ part, int nb) {
    __shared__ int s[256];
    int tid = threadIdx.x;
    int v = (tid < nb) ? part[tid] : 0;
    s[tid] = v;
    __syncthreads();
    for (int off = 1; off < 256; off <<= 1) {
        int t = (tid >= off) ? s[tid - off] : 0;
        __syncthreads();
        s[tid] += t;
        __syncthreads();
    }
    if (tid < nb) part[tid] = s[tid] - v;
}

__global__ __launch_bounds__(256) void k_scan3(int* __restrict__ offs, const int* __restrict__ part,
                                               int n, int E) {
    int gid = blockIdx.x * 256 + threadIdx.x;
    if (gid < n) offs[gid] += part[blockIdx.x];
    if (gid == 0) offs[n] = E;
}

// ---------------- CSR fill: no atomics; chunk base row staged in LDS -----------
__global__ __launch_bounds__(256) void k_csr_fill(const int* __restrict__ ei, int E, int CE,
                                                  const int* __restrict__ offs,
                                                  const unsigned* __restrict__ partial,
                                                  const ushort* __restrict__ lrank,
                                                  int* __restrict__ csrc) {
    __shared__ unsigned lp[PITCH];
    const int b = blockIdx.x, tid = threadIdx.x;
    const unsigned* prow = partial + (size_t)b * PITCH;
    for (int w = tid; w < PITCH; w += 256) lp[w] = prow[w];
    __syncthreads();
    int e0 = b * CE, e1 = min(E, e0 + CE);
    for (int e = e0 + tid; e < e1; e += 256) {
        int dst = ei[E + e];
        int src = ei[e];
        unsigned wv = lp[dst >> 2];
        int base = (wv >> ((dst & 3) * 8)) & 0xffu;
        csrc[offs[dst] + base + (int)lrank[e]] = src;
    }
}

// ---------------- GEMM1: h = relu(x @ W1^T + b1), MFMA bf16 -------------------
__global__ __launch_bounds__(256) void k_gemm1(const float* __restrict__ x,
                                               const float* __restrict__ W1,
                                               const float* __restrict__ b1,
                                               float* __restrict__ h, int M) {
    __shared__ ushort As[BM1 * LDST];
    __shared__ ushort Bs[128 * LDST];
    const int tid = threadIdx.x;
    const int bm = blockIdx.x * BM1;
    const int wave = tid >> 6, lane = tid & 63;
    const int rh = (wave >> 1) * 32;   // wave row offset: 0 / 32
    const int ch = (wave & 1) * 64;    // wave col offset: 0 / 64
    const int sub = lane & 15, quad = lane >> 4;
    const int lrow = tid >> 3;         // 0..31
    const int lcol = (tid & 7) * 4;    // 0..28
    f32x4 acc[2][4] = {};
    float4 av[2], bv[4];
    // prologue: load K-tile 0 into registers
#pragma unroll
    for (int i = 0; i < 2; ++i) {
        int grow = bm + lrow + 32 * i;
        av[i] = (grow < M) ? *(const float4*)(x + (size_t)grow * FEAT + lcol)
                           : make_float4(0.f, 0.f, 0.f, 0.f);
    }
#pragma unroll
    for (int i = 0; i < 4; ++i)
        bv[i] = *(const float4*)(W1 + (size_t)(lrow + 32 * i) * FEAT + lcol);

    for (int k0 = 0; k0 < FEAT; k0 += 32) {
        // stage current tile regs -> LDS (bf16 pack)
#pragma unroll
        for (int i = 0; i < 2; ++i)
            *(uint2*)(As + (lrow + 32 * i) * LDST + lcol) =
                make_uint2(pack_bf16(av[i].x, av[i].y), pack_bf16(av[i].z, av[i].w));
#pragma unroll
        for (int i = 0; i < 4; ++i)
            *(uint2*)(Bs + (lrow + 32 * i) * LDST + lcol) =
                make_uint2(pack_bf16(bv[i].x, bv[i].y), pack_bf16(bv[i].z, bv[i].w));
        __syncthreads();
        // prefetch next K-tile into registers (overlaps ds_read + MFMA below)
        if (k0 + 32 < FEAT) {
            const int kn = k0 + 32;
#pragma unroll
            for (int i = 0; i < 2; ++i) {
                int grow = bm + lrow + 32 * i;
                av[i] = (grow < M) ? *(const float4*)(x + (size_t)grow * FEAT + kn + lcol)
                                   : make_float4(0.f, 0.f, 0.f, 0.f);
            }
#pragma unroll
            for (int i = 0; i < 4; ++i)
                bv[i] = *(const float4*)(W1 + (size_t)(lrow + 32 * i) * FEAT + kn + lcol);
        }
        short8 af[2], bfr[4];
#pragma unroll
        for (int t = 0; t < 2; ++t)
            af[t] = *(const short8*)(As + (rh + t * 16 + sub) * LDST + quad * 8);
#pragma unroll
        for (int u = 0; u < 4; ++u)
            bfr[u] = *(const short8*)(Bs + (ch + u * 16 + sub) * LDST + quad * 8);
#pragma unroll
        for (int t = 0; t < 2; ++t)
#pragma unroll
            for (int u = 0; u < 4; ++u)
                acc[t][u] = __builtin_amdgcn_mfma_f32_16x16x32_bf16(af[t], bfr[u], acc[t][u], 0, 0, 0);
        __syncthreads();
    }
    float b1v[4];
#pragma unroll
    for (int u = 0; u < 4; ++u) b1v[u] = b1[ch + u * 16 + sub];
#pragma unroll
    for (int t = 0; t < 2; ++t) {
#pragma unroll
        for (int u = 0; u < 4; ++u) {
            int col = ch + u * 16 + sub;
#pragma unroll
            for (int r2 = 0; r2 < 4; ++r2) {
                int grow = bm + rh + t * 16 + quad * 4 + r2;
                if (grow < M)
                    h[(size_t)grow * HIDDEN + col] = fmaxf(acc[t][u][r2] + b1v[u], 0.f);
            }
        }
    }
}

// ---------------- prep: bf16 pack + layer-0 dots -> {al,dis}, ar ----------------
__global__ __launch_bounds__(256) void k_prep(const float* __restrict__ h, unsigned* __restrict__ hbf,
                       const float* __restrict__ attl, const float* __restrict__ attr,
                       const float* __restrict__ dis, float2* __restrict__ al2,
                       float* __restrict__ ar, int n) {
    int node = (blockIdx.x * blockDim.x + threadIdx.x) >> 6;
    int lane = threadIdx.x & 63;
    if (node >= n) return;
    float2 hv = ((const float2*)(h + (size_t)node * HIDDEN))[lane];
    hbf[(size_t)node * 64 + lane] = pack_bf16(hv.x, hv.y);
    float pl = hv.x * attl[2 * lane] + hv.y * attl[2 * lane + 1];
    float pr = hv.x * attr[2 * lane] + hv.y * attr[2 * lane + 1];
    for (int off = 32; off; off >>= 1) {
        pl += __shfl_down(pl, off);
        pr += __shfl_down(pr, off);
    }
    if (lane == 0) {
        al2[node] = make_float2(pl, dis[node]);
        ar[node] = pr;
    }
}

// ---------------- aggregate: phase-1 coef batch + 2-deep pipelined gathers -----
// Phase-1 computes 64 coefs (one/lane). Phase-2 processes 16-edge blocks with
// the NEXT block's 4 uint4 gathers issued before the current block's FMAs
// (8 gathers in flight/lane at steady state). VGPR kept < 64 (occupancy cliff).
__global__ __launch_bounds__(256) void k_aggregate(
                            const unsigned* __restrict__ hbf, const float* __restrict__ raw,
                            const float2* __restrict__ al2, const float* __restrict__ ar,
                            const int* __restrict__ offs, const int* __restrict__ csrc,
                            float* __restrict__ hout, unsigned* __restrict__ houtbf,
                            const float* __restrict__ attl_n, const float* __restrict__ attr_n,
                            float2* __restrict__ al2_o, float* __restrict__ ar_o, int n) {
    int node = (blockIdx.x * blockDim.x + threadIdx.x) >> 6;
    int lane = threadIdx.x & 63;
    if (node >= n) return;
    const int grp = lane >> 4;
    const int sub = lane & 15;
    const float arn = ar[node];
    const float2 selfld = al2[node];
    const float disn = selfld.y;
    float acc[8] = {0.f, 0.f, 0.f, 0.f, 0.f, 0.f, 0.f, 0.f};
    int e0 = offs[node], e1 = offs[node + 1];
    for (int base = e0; base < e1; base += 64) {
        int cnt = min(64, e1 - base);
        // phase 1: one coef per lane (zero-padded past cnt)
        int idx = base + lane;
        int smy = (lane < cnt) ? csrc[idx] : node;
        float2 lmy = al2[smy];
        float cmy = (lane < cnt) ? fast_tanh(lmy.x + arn) * lmy.y * disn : 0.f;
        // phase 2: 16-edge blocks, 2-deep pipelined
        int t = 0;
        if (t + 16 <= cnt) {
            float ca = __shfl(cmy, t + grp);
            float cb = __shfl(cmy, t + 4 + grp);
            float cc = __shfl(cmy, t + 8 + grp);
            float cd = __shfl(cmy, t + 12 + grp);
            uint4 ra = *(const uint4*)(hbf + (size_t)__shfl(smy, t + grp) * 64 + sub * 4);
            uint4 rb = *(const uint4*)(hbf + (size_t)__shfl(smy, t + 4 + grp) * 64 + sub * 4);
            uint4 rc = *(const uint4*)(hbf + (size_t)__shfl(smy, t + 8 + grp) * 64 + sub * 4);
            uint4 rd = *(const uint4*)(hbf + (size_t)__shfl(smy, t + 12 + grp) * 64 + sub * 4);
            for (; t + 32 <= cnt; t += 16) {
                const int t2 = t + 16;
                float ca2 = __shfl(cmy, t2 + grp);
                float cb2 = __shfl(cmy, t2 + 4 + grp);
                float cc2 = __shfl(cmy, t2 + 8 + grp);
                float cd2 = __shfl(cmy, t2 + 12 + grp);
                uint4 ra2 = *(const uint4*)(hbf + (size_t)__shfl(smy, t2 + grp) * 64 + sub * 4);
                uint4 rb2 = *(const uint4*)(hbf + (size_t)__shfl(smy, t2 + 4 + grp) * 64 + sub * 4);
                uint4 rc2 = *(const uint4*)(hbf + (size_t)__shfl(smy, t2 + 8 + grp) * 64 + sub * 4);
                uint4 rd2 = *(const uint4*)(hbf + (size_t)__shfl(smy, t2 + 12 + grp) * 64 + sub * 4);
                ACC4(ca, ra); ACC4(cb, rb); ACC4(cc, rc); ACC4(cd, rd);
                ca = ca2; cb = cb2; cc = cc2; cd = cd2;
                ra = ra2; rb = rb2; rc = rc2; rd = rd2;
            }
            ACC4(ca, ra); ACC4(cb, rb); ACC4(cc, rc); ACC4(cd, rd);
            t += 16;
        }
        for (; t < cnt; t += 4) {   // zero-padded tail (covers 1-3 leftovers too)
            int sa = __shfl(smy, t + grp);
            float ca = __shfl(cmy, t + grp);
            uint4 ra = *(const uint4*)(hbf + (size_t)sa * 64 + sub * 4);
            ACC4(ca, ra);
        }
    }
#pragma unroll
    for (int j = 0; j < 8; ++j) {
        acc[j] += __shfl_xor(acc[j], 16);
        acc[j] += __shfl_xor(acc[j], 32);
    }
    {   // self-loop term (post-reduce, replicated across groups)
        float c = fast_tanh(selfld.x + arn) * disn * disn;
        uint4 r = *(const uint4*)(hbf + (size_t)node * 64 + sub * 4);
        ACC4(c, r);
    }
    float o[8];
    {
        float4 rv0 = *(const float4*)(raw + (size_t)node * HIDDEN + sub * 8);
        float4 rv1 = *(const float4*)(raw + (size_t)node * HIDDEN + sub * 8 + 4);
        o[0] = acc[0] + 0.3f * rv0.x; o[1] = acc[1] + 0.3f * rv0.y;
        o[2] = acc[2] + 0.3f * rv0.z; o[3] = acc[3] + 0.3f * rv0.w;
        o[4] = acc[4] + 0.3f * rv1.x; o[5] = acc[5] + 0.3f * rv1.y;
        o[6] = acc[6] + 0.3f * rv1.z; o[7] = acc[7] + 0.3f * rv1.w;
    }
    if (grp == 0) {
        *(float4*)(hout + (size_t)node * HIDDEN + sub * 8) = make_float4(o[0], o[1], o[2], o[3]);
        *(float4*)(hout + (size_t)node * HIDDEN + sub * 8 + 4) = make_float4(o[4], o[5], o[6], o[7]);
        if (houtbf) {
            uint4 pk = make_uint4(pack_bf16(o[0], o[1]), pack_bf16(o[2], o[3]),
                                  pack_bf16(o[4], o[5]), pack_bf16(o[6], o[7]));
            *(uint4*)(houtbf + (size_t)node * 64 + sub * 4) = pk;
        }
    }
    if (attl_n) {
        float4 a0 = *(const float4*)(attl_n + sub * 8);
        float4 a1 = *(const float4*)(attl_n + sub * 8 + 4);
        float4 c0 = *(const float4*)(attr_n + sub * 8);
        float4 c1 = *(const float4*)(attr_n + sub * 8 + 4);
        float pl = o[0] * a0.x + o[1] * a0.y + o[2] * a0.z + o[3] * a0.w +
                   o[4] * a1.x + o[5] * a1.y + o[6] * a1.z + o[7] * a1.w;
        float pr = o[0] * c0.x + o[1] * c0.y + o[2] * c0.z + o[3] * c0.w +
                   o[4] * c1.x + o[5] * c1.y + o[6] * c1.z + o[7] * c1.w;
        for (int off = 8; off; off >>= 1) {
            pl += __shfl_xor(pl, off);
            pr += __shfl_xor(pr, off);
        }
        if (lane == 0) {
            al2_o[node] = make_float2(pl, disn);
            ar_o[node] = pr;
        }
    }
}

// ---------------- output: log_softmax(h @ W2^T + b2) ---------------------------
__global__ __launch_bounds__(256, 4) void k_out(const float* __restrict__ h,
                                                const float* __restrict__ W2,
                                                const float* __restrict__ b2,
                                                float* __restrict__ out, int n) {
    __shared__ float ws[NCLASS * LDSW];
    __shared__ float bs[NCLASS];
    const int tid = threadIdx.x;
    for (int i = tid; i < NCLASS * (HIDDEN / 4); i += 256) {
        int r = i >> 5;          // row (class), 32 float4 per row
        int c4 = i & 31;         // float4 index within row
        *(float4*)(ws + r * LDSW + c4 * 4) = ((const float4*)W2)[i];
    }
    if (tid < NCLASS) bs[tid] = b2[tid];
    __syncthreads();
    int node = blockIdx.x * 32 + (tid >> 3);
    const int ol = tid & 7;
    if (node >= n) return;
    const float* hr = h + (size_t)node * HIDDEN;
    float acc[5];
#pragma unroll
    for (int c = 0; c < 5; ++c) acc[c] = bs[ol + 8 * c];
#pragma unroll
    for (int k0 = 0; k0 < HIDDEN; k0 += 16) {
        float4 h0 = *(const float4*)(hr + k0);
        float4 h1 = *(const float4*)(hr + k0 + 4);
        float4 h2v = *(const float4*)(hr + k0 + 8);
        float4 h3 = *(const float4*)(hr + k0 + 12);
#pragma unroll
        for (int c = 0; c < 5; ++c) {
            const float* w = ws + (ol + 8 * c) * LDSW + k0;
            float4 w0 = *(const float4*)(w);
            float4 w1 = *(const float4*)(w + 4);
            float4 w2v = *(const float4*)(w + 8);
            float4 w3 = *(const float4*)(w + 12);
            acc[c] += h0.x * w0.x + h0.y * w0.y + h0.z * w0.z + h0.w * w0.w +
                      h1.x * w1.x + h1.y * w1.y + h1.z * w1.z + h1.w * w1.w +
                      h2v.x * w2v.x + h2v.y * w2v.y + h2v.z * w2v.z + h2v.w * w2v.w +
                      h3.x * w3.x + h3.y * w3.y + h3.z * w3.z + h3.w * w3.w;
        }
    }
    float m = acc[0];
#pragma unroll
    for (int c = 1; c < 5; ++c) m = fmaxf(m, acc[c]);
    m = fmaxf(m, __shfl_xor(m, 1));
    m = fmaxf(m, __shfl_xor(m, 2));
    m = fmaxf(m, __shfl_xor(m, 4));
    float ssum = 0.f;
#pragma unroll
    for (int c = 0; c < 5; ++c) ssum += expf(acc[c] - m);
    ssum += __shfl_xor(ssum, 1);
    ssum += __shfl_xor(ssum, 2);
    ssum += __shfl_xor(ssum, 4);
    float lse = m + logf(ssum);
    float* orow = out + (size_t)node * NCLASS;
#pragma unroll
    for (int c = 0; c < 5; ++c) orow[ol + 8 * c] = acc[c] - lse;
}

extern "C" void kernel_launch(void* const* d_in, const int* in_sizes, int n_in,
                              void* d_out, int out_size, void* d_ws, size_t ws_size,
                              hipStream_t stream) {
    const float* x    = (const float*)d_in[0];
    const int*   ei   = (const int*)d_in[1];
    const float* W1   = (const float*)d_in[2];
    const float* b1   = (const float*)d_in[3];
    const float* W2   = (const float*)d_in[4];
    const float* b2   = (const float*)d_in[5];
    const float* attl = (const float*)d_in[6];
    const float* attr = (const float*)d_in[7];
    const int N = in_sizes[0] / FEAT;
    const int E = in_sizes[1] / 2;
    float* out = (float*)d_out;

    char* p = (char*)d_ws;
    auto take = [&](size_t bytes) {
        void* q = (void*)p;
        p += (bytes + 255) & ~(size_t)255;
        return q;
    };
    float*    h0   = (float*)take((size_t)N * HIDDEN * 4);  // = raw
    float*    h1   = (float*)take((size_t)N * HIDDEN * 4);
    float*    h2   = (float*)take((size_t)N * HIDDEN * 4);
    unsigned* hb0  = (unsigned*)take((size_t)N * 64 * 4);
    unsigned* hb1  = (unsigned*)take((size_t)N * 64 * 4);
    int*      deg  = (int*)take((size_t)N * 4);
    float*    dis  = (float*)take((size_t)N * 4);
    int*      offs = (int*)take((size_t)(N + 1) * 4);
    unsigned* partial = (unsigned*)take((size_t)NB * PITCH * 4);
    ushort*   lrank   = (ushort*)take((size_t)E * 2);
    int*      csrc = (int*)take((size_t)E * 4);
    float2*   al2A = (float2*)take((size_t)N * 8);
    float2*   al2B = (float2*)take((size_t)N * 8);
    float*    arA  = (float*)take((size_t)N * 4);
    float*    arB  = (float*)take((size_t)N * 4);
    int*      part = (int*)take(1024);

    const int nbl = (N + 255) / 256;
    const int CE = (E + NB - 1) / NB;

    k_hist<<<NB, 256, 0, stream>>>(ei, E, CE, partial, lrank);
    k_hscan<<<(PITCH + 255) / 256, 256, 0, stream>>>(partial, deg, dis, N);
    k_scan1<<<nbl, 256, 0, stream>>>(deg, offs, part, N);
    k_scan2<<<1, 256, 0, stream>>>(part, nbl);
    k_scan3<<<nbl, 256, 0, stream>>>(offs, part, N, E);
    k_csr_fill<<<NB, 256, 0, stream>>>(ei, E, CE, offs, partial, lrank, csrc);

    k_gemm1<<<(N + BM1 - 1) / BM1, 256, 0, stream>>>(x, W1, b1, h0, N);
    k_prep<<<(N + 3) / 4, 256, 0, stream>>>(h0, hb0, attl, attr, dis, al2A, arA, N);

    float*    fout[4] = {h1, h2, h1, h2};
    unsigned* hbin = hb0, *hbout = hb1;
    float2*   alin = al2A, *alout = al2B;
    float*    arin = arA,  *arout = arB;
    for (int l = 0; l < 4; ++l) {
        const float* attl_n = (l < 3) ? (attl + (l + 1) * HIDDEN) : nullptr;
        const float* attr_n = (l < 3) ? (attr + (l + 1) * HIDDEN) : nullptr;
        unsigned* hbo = (l < 3) ? hbout : nullptr;
        k_aggregate<<<(N + 3) / 4, 256, 0, stream>>>(hbin, h0, alin, arin, offs, csrc,
                                                     fout[l], hbo, attl_n, attr_n,
                                                     alout, arout, N);
        unsigned* tb = hbin; hbin = hbout; hbout = tb;
        float2* ta = alin; alin = alout; alout = ta;
        float* tr = arin; arin = arout; arout = tr;
    }

    k_out<<<(N + 31) / 32, 256, 0, stream>>>(h2, W2, b2, out, N);
}

// Round 8
// 517.051 us; speedup vs baseline: 1.2500x; 1.0115x over previous
//
#include <hip/hip_runtime.h>
#include <cmath>

// FAGCN: N=50000, E=1.6M, FEAT=512, HIDDEN=128, CLASS=40, 4 layers, eps=0.3
// R17 = R16 resubmitted verbatim (R16 bench failed on container infra, never
// measured). k_aggregate inner loop uses packed math — acc held as f32x2[4],
// accumulate via __builtin_elementwise_fma on ext_vector float2
// (ISel -> v_pk_fma_f32: 8 unpack + 4 pk_fma = 12 VALU/uint4 vs 16 before).
// R15 post-mortem: manual 2-deep gather pipeline was NULL (compiler already
// pipelines; VGPR unchanged 36). Agg counters: VALU 52%, fetch 3.57 TB/s,
// occ 64% — mixed; VALU count is the remaining attackable term. All other
// kernels byte-identical to R15 for attribution. Pre-commit: null => agg is
// memory-structural; pivot to mid-tier attribution next.

#define HIDDEN 128
#define FEAT 512
#define NCLASS 40
#define LDST 40    // GEMM LDS row stride in ushorts (80 B)
#define LDSW 132   // k_out ws row stride in floats (528 B -> 4-bank shift/row)
#define NB 256     // histogram chunks (= blocks)
#define PITCH 12544  // words per partial row: 4 nodes/word -> supports N<=50176
#define BM1 64     // k_gemm1 M-tile

typedef __attribute__((ext_vector_type(8))) short short8;
typedef __attribute__((ext_vector_type(4))) float f32x4;
typedef __attribute__((ext_vector_type(2))) float f32x2;

__device__ __forceinline__ float bf_lo(unsigned u) { return __uint_as_float(u << 16); }
__device__ __forceinline__ float bf_hi(unsigned u) { return __uint_as_float(u & 0xffff0000u); }
__device__ __forceinline__ f32x2 up2(unsigned u) {
    f32x2 v; v.x = bf_lo(u); v.y = bf_hi(u); return v;
}
__device__ __forceinline__ unsigned pack_bf16(float x, float y) {
    unsigned ux = __float_as_uint(x);
    unsigned uy = __float_as_uint(y);
    unsigned lx = (ux + 0x7fffu + ((ux >> 16) & 1u)) >> 16;
    unsigned hy = (uy + 0x7fffu + ((uy >> 16) & 1u)) & 0xffff0000u;
    return hy | lx;
}
__device__ __forceinline__ float fast_tanh(float x) {
    x = fminf(fmaxf(x, -15.f), 15.f);
    float e = __expf(2.f * x);
    return (e - 1.f) / (e + 1.f);
}

// packed accumulate: 4x v_pk_fma_f32 per uint4
#define ACC4P(c, r) { f32x2 c2; c2.x = c; c2.y = c; \
    acc2[0] = __builtin_elementwise_fma(c2, up2(r.x), acc2[0]); \
    acc2[1] = __builtin_elementwise_fma(c2, up2(r.y), acc2[1]); \
    acc2[2] = __builtin_elementwise_fma(c2, up2(r.z), acc2[2]); \
    acc2[3] = __builtin_elementwise_fma(c2, up2(r.w), acc2[3]); }

// ---------------- per-chunk LDS histogram (8-bit packed) + local rank ----------
__global__ __launch_bounds__(256) void k_hist(const int* __restrict__ ei, int E, int CE,
                                              unsigned* __restrict__ partial,
                                              ushort* __restrict__ lrank) {
    __shared__ unsigned lh[PITCH];
    const int b = blockIdx.x, tid = threadIdx.x;
    for (int w = tid; w < PITCH; w += 256) lh[w] = 0;
    __syncthreads();
    int e0 = b * CE, e1 = min(E, e0 + CE);
    for (int e = e0 + tid; e < e1; e += 256) {
        int dst = ei[E + e];
        int sh = (dst & 3) * 8;
        unsigned old = atomicAdd(&lh[dst >> 2], 1u << sh);
        lrank[e] = (ushort)((old >> sh) & 0xffu);
    }
    __syncthreads();
    unsigned* prow = partial + (size_t)b * PITCH;
    for (int w = tid; w < PITCH; w += 256) prow[w] = lh[w];
}

// ---------------- cross-chunk exclusive scan (in place) + degree + dis ---------
__global__ __launch_bounds__(256) void k_hscan(unsigned* __restrict__ partial,
                                               int* __restrict__ deg,
                                               float* __restrict__ dis, int n) {
    int w = blockIdx.x * 256 + threadIdx.x;
    if (w >= PITCH) return;
    unsigned run = 0;
    size_t idx = w;
    for (int b = 0; b < NB; ++b, idx += PITCH) {
        unsigned v = partial[idx];
        partial[idx] = run;
        run += v;
    }
    int node = 4 * w;
    int d0 = run & 0xffu, d1 = (run >> 8) & 0xffu, d2 = (run >> 16) & 0xffu, d3 = run >> 24;
    if (node < n)     { deg[node]     = d0; dis[node]     = rsqrtf((float)(d0 + 1)); }
    if (node + 1 < n) { deg[node + 1] = d1; dis[node + 1] = rsqrtf((float)(d1 + 1)); }
    if (node + 2 < n) { deg[node + 2] = d2; dis[node + 2] = rsqrtf((float)(d2 + 1)); }
    if (node + 3 < n) { deg[node + 3] = d3; dis[node + 3] = rsqrtf((float)(d3 + 1)); }
}

// ---------------- exclusive scan over node degrees (offs) ----------------
__global__ __launch_bounds__(256) void k_scan1(const int* __restrict__ deg, int* __restrict__ offs,
                                               int* __restrict__ part, int n) {
    __shared__ int s[256];
    int tid = threadIdx.x;
    int gid = blockIdx.x * 256 + tid;
    int v = (gid < n) ? deg[gid] : 0;
    s[tid] = v;
    __syncthreads();
    for (int off = 1; off < 256; off <<= 1) {
        int t = (tid >= off) ? s[tid - off] : 0;
        __syncthreads();
        s[tid] += t;
        __syncthreads();
    }
    if (gid < n) offs[gid] = s[tid] - v;
    if (tid == 255) part[blockIdx.x] = s[255];
}

__global__ __launch_bounds__(256) void k_scan2(int* __restrict__ part, int nb) {
    __shared__ int s[256];
    int tid = threadIdx.x;
    int v = (tid < nb) ? part[tid] : 0;
    s[tid] = v;
    __syncthreads();
    for (int off = 1; off < 256; off <<= 1) {
        int t = (tid >= off) ? s[tid - off] : 0;
        __syncthreads();
        s[tid] += t;
        __syncthreads();
    }
    if (tid < nb) part[tid] = s[tid] - v;
}

__global__ __launch_bounds__(256) void k_scan3(int* __restrict__ offs, const int* __restrict__ part,
                                               int n, int E) {
    int gid = blockIdx.x * 256 + threadIdx.x;
    if (gid < n) offs[gid] += part[blockIdx.x];
    if (gid == 0) offs[n] = E;
}

// ---------------- CSR fill: no atomics; chunk base row staged in LDS -----------
__global__ __launch_bounds__(256) void k_csr_fill(const int* __restrict__ ei, int E, int CE,
                                                  const int* __restrict__ offs,
                                                  const unsigned* __restrict__ partial,
                                                  const ushort* __restrict__ lrank,
                                                  int* __restrict__ csrc) {
    __shared__ unsigned lp[PITCH];
    const int b = blockIdx.x, tid = threadIdx.x;
    const unsigned* prow = partial + (size_t)b * PITCH;
    for (int w = tid; w < PITCH; w += 256) lp[w] = prow[w];
    __syncthreads();
    int e0 = b * CE, e1 = min(E, e0 + CE);
    for (int e = e0 + tid; e < e1; e += 256) {
        int dst = ei[E + e];
        int src = ei[e];
        unsigned wv = lp[dst >> 2];
        int base = (wv >> ((dst & 3) * 8)) & 0xffu;
        csrc[offs[dst] + base + (int)lrank[e]] = src;
    }
}

// ---------------- GEMM1: h = relu(x @ W1^T + b1), MFMA bf16 -------------------
__global__ __launch_bounds__(256) void k_gemm1(const float* __restrict__ x,
                                               const float* __restrict__ W1,
                                               const float* __restrict__ b1,
                                               float* __restrict__ h, int M) {
    __shared__ ushort As[BM1 * LDST];
    __shared__ ushort Bs[128 * LDST];
    const int tid = threadIdx.x;
    const int bm = blockIdx.x * BM1;
    const int wave = tid >> 6, lane = tid & 63;
    const int rh = (wave >> 1) * 32;   // wave row offset: 0 / 32
    const int ch = (wave & 1) * 64;    // wave col offset: 0 / 64
    const int sub = lane & 15, quad = lane >> 4;
    const int lrow = tid >> 3;         // 0..31
    const int lcol = (tid & 7) * 4;    // 0..28
    f32x4 acc[2][4] = {};
    float4 av[2], bv[4];
    // prologue: load K-tile 0 into registers
#pragma unroll
    for (int i = 0; i < 2; ++i) {
        int grow = bm + lrow + 32 * i;
        av[i] = (grow < M) ? *(const float4*)(x + (size_t)grow * FEAT + lcol)
                           : make_float4(0.f, 0.f, 0.f, 0.f);
    }
#pragma unroll
    for (int i = 0; i < 4; ++i)
        bv[i] = *(const float4*)(W1 + (size_t)(lrow + 32 * i) * FEAT + lcol);

    for (int k0 = 0; k0 < FEAT; k0 += 32) {
        // stage current tile regs -> LDS (bf16 pack)
#pragma unroll
        for (int i = 0; i < 2; ++i)
            *(uint2*)(As + (lrow + 32 * i) * LDST + lcol) =
                make_uint2(pack_bf16(av[i].x, av[i].y), pack_bf16(av[i].z, av[i].w));
#pragma unroll
        for (int i = 0; i < 4; ++i)
            *(uint2*)(Bs + (lrow + 32 * i) * LDST + lcol) =
                make_uint2(pack_bf16(bv[i].x, bv[i].y), pack_bf16(bv[i].z, bv[i].w));
        __syncthreads();
        // prefetch next K-tile into registers (overlaps ds_read + MFMA below)
        if (k0 + 32 < FEAT) {
            const int kn = k0 + 32;
#pragma unroll
            for (int i = 0; i < 2; ++i) {
                int grow = bm + lrow + 32 * i;
                av[i] = (grow < M) ? *(const float4*)(x + (size_t)grow * FEAT + kn + lcol)
                                   : make_float4(0.f, 0.f, 0.f, 0.f);
            }
#pragma unroll
            for (int i = 0; i < 4; ++i)
                bv[i] = *(const float4*)(W1 + (size_t)(lrow + 32 * i) * FEAT + kn + lcol);
        }
        short8 af[2], bfr[4];
#pragma unroll
        for (int t = 0; t < 2; ++t)
            af[t] = *(const short8*)(As + (rh + t * 16 + sub) * LDST + quad * 8);
#pragma unroll
        for (int u = 0; u < 4; ++u)
            bfr[u] = *(const short8*)(Bs + (ch + u * 16 + sub) * LDST + quad * 8);
#pragma unroll
        for (int t = 0; t < 2; ++t)
#pragma unroll
            for (int u = 0; u < 4; ++u)
                acc[t][u] = __builtin_amdgcn_mfma_f32_16x16x32_bf16(af[t], bfr[u], acc[t][u], 0, 0, 0);
        __syncthreads();
    }
    float b1v[4];
#pragma unroll
    for (int u = 0; u < 4; ++u) b1v[u] = b1[ch + u * 16 + sub];
#pragma unroll
    for (int t = 0; t < 2; ++t) {
#pragma unroll
        for (int u = 0; u < 4; ++u) {
            int col = ch + u * 16 + sub;
#pragma unroll
            for (int r2 = 0; r2 < 4; ++r2) {
                int grow = bm + rh + t * 16 + quad * 4 + r2;
                if (grow < M)
                    h[(size_t)grow * HIDDEN + col] = fmaxf(acc[t][u][r2] + b1v[u], 0.f);
            }
        }
    }
}

// ---------------- prep: bf16 pack + layer-0 dots -> {al,dis}, ar ----------------
__global__ __launch_bounds__(256) void k_prep(const float* __restrict__ h, unsigned* __restrict__ hbf,
                       const float* __restrict__ attl, const float* __restrict__ attr,
                       const float* __restrict__ dis, float2* __restrict__ al2,
                       float* __restrict__ ar, int n) {
    int node = (blockIdx.x * blockDim.x + threadIdx.x) >> 6;
    int lane = threadIdx.x & 63;
    if (node >= n) return;
    float2 hv = ((const float2*)(h + (size_t)node * HIDDEN))[lane];
    hbf[(size_t)node * 64 + lane] = pack_bf16(hv.x, hv.y);
    float pl = hv.x * attl[2 * lane] + hv.y * attl[2 * lane + 1];
    float pr = hv.x * attr[2 * lane] + hv.y * attr[2 * lane + 1];
    for (int off = 32; off; off >>= 1) {
        pl += __shfl_down(pl, off);
        pr += __shfl_down(pr, off);
    }
    if (lane == 0) {
        al2[node] = make_float2(pl, dis[node]);
        ar[node] = pr;
    }
}

// ---------------- aggregate: phase-1 coef batch + packed-FMA hot loop ----------
__global__ __launch_bounds__(256) void k_aggregate(
                            const unsigned* __restrict__ hbf, const float* __restrict__ raw,
                            const float2* __restrict__ al2, const float* __restrict__ ar,
                            const int* __restrict__ offs, const int* __restrict__ csrc,
                            float* __restrict__ hout, unsigned* __restrict__ houtbf,
                            const float* __restrict__ attl_n, const float* __restrict__ attr_n,
                            float2* __restrict__ al2_o, float* __restrict__ ar_o, int n) {
    int node = (blockIdx.x * blockDim.x + threadIdx.x) >> 6;
    int lane = threadIdx.x & 63;
    if (node >= n) return;
    const int grp = lane >> 4;
    const int sub = lane & 15;
    const float arn = ar[node];
    const float2 selfld = al2[node];
    const float disn = selfld.y;
    f32x2 acc2[4] = {};
    int e0 = offs[node], e1 = offs[node + 1];
    for (int base = e0; base < e1; base += 64) {
        int cnt = min(64, e1 - base);
        // phase 1: one coef per lane (zero-padded past cnt)
        int idx = base + lane;
        int smy = (lane < cnt) ? csrc[idx] : node;
        float2 lmy = al2[smy];
        float cmy = (lane < cnt) ? fast_tanh(lmy.x + arn) * lmy.y * disn : 0.f;
        // phase 2: 16-edge hot loop, src/coef via shfl, packed FMA
        int t = 0;
        for (; t + 16 <= cnt; t += 16) {
            int sa = __shfl(smy, t + grp);
            int sb = __shfl(smy, t + 4 + grp);
            int sc = __shfl(smy, t + 8 + grp);
            int sd = __shfl(smy, t + 12 + grp);
            float ca = __shfl(cmy, t + grp);
            float cb = __shfl(cmy, t + 4 + grp);
            float cc = __shfl(cmy, t + 8 + grp);
            float cd = __shfl(cmy, t + 12 + grp);
            uint4 ra = *(const uint4*)(hbf + (size_t)sa * 64 + sub * 4);
            uint4 rb = *(const uint4*)(hbf + (size_t)sb * 64 + sub * 4);
            uint4 rc = *(const uint4*)(hbf + (size_t)sc * 64 + sub * 4);
            uint4 rd = *(const uint4*)(hbf + (size_t)sd * 64 + sub * 4);
            ACC4P(ca, ra); ACC4P(cb, rb); ACC4P(cc, rc); ACC4P(cd, rd);
        }
        for (; t < cnt; t += 4) {   // zero-padded tail (covers 1-3 leftovers too)
            int sa = __shfl(smy, t + grp);
            float ca = __shfl(cmy, t + grp);
            uint4 ra = *(const uint4*)(hbf + (size_t)sa * 64 + sub * 4);
            ACC4P(ca, ra);
        }
    }
#pragma unroll
    for (int j = 0; j < 4; ++j) {
        acc2[j].x += __shfl_xor(acc2[j].x, 16);
        acc2[j].y += __shfl_xor(acc2[j].y, 16);
        acc2[j].x += __shfl_xor(acc2[j].x, 32);
        acc2[j].y += __shfl_xor(acc2[j].y, 32);
    }
    {   // self-loop term (post-reduce, replicated across groups)
        float c = fast_tanh(selfld.x + arn) * disn * disn;
        uint4 r = *(const uint4*)(hbf + (size_t)node * 64 + sub * 4);
        ACC4P(c, r);
    }
    float o[8];
    {
        float4 rv0 = *(const float4*)(raw + (size_t)node * HIDDEN + sub * 8);
        float4 rv1 = *(const float4*)(raw + (size_t)node * HIDDEN + sub * 8 + 4);
        o[0] = acc2[0].x + 0.3f * rv0.x; o[1] = acc2[0].y + 0.3f * rv0.y;
        o[2] = acc2[1].x + 0.3f * rv0.z; o[3] = acc2[1].y + 0.3f * rv0.w;
        o[4] = acc2[2].x + 0.3f * rv1.x; o[5] = acc2[2].y + 0.3f * rv1.y;
        o[6] = acc2[3].x + 0.3f * rv1.z; o[7] = acc2[3].y + 0.3f * rv1.w;
    }
    if (grp == 0) {
        *(float4*)(hout + (size_t)node * HIDDEN + sub * 8) = make_float4(o[0], o[1], o[2], o[3]);
        *(float4*)(hout + (size_t)node * HIDDEN + sub * 8 + 4) = make_float4(o[4], o[5], o[6], o[7]);
        if (houtbf) {
            uint4 pk = make_uint4(pack_bf16(o[0], o[1]), pack_bf16(o[2], o[3]),
                                  pack_bf16(o[4], o[5]), pack_bf16(o[6], o[7]));
            *(uint4*)(houtbf + (size_t)node * 64 + sub * 4) = pk;
        }
    }
    if (attl_n) {
        float4 a0 = *(const float4*)(attl_n + sub * 8);
        float4 a1 = *(const float4*)(attl_n + sub * 8 + 4);
        float4 c0 = *(const float4*)(attr_n + sub * 8);
        float4 c1 = *(const float4*)(attr_n + sub * 8 + 4);
        float pl = o[0] * a0.x + o[1] * a0.y + o[2] * a0.z + o[3] * a0.w +
                   o[4] * a1.x + o[5] * a1.y + o[6] * a1.z + o[7] * a1.w;
        float pr = o[0] * c0.x + o[1] * c0.y + o[2] * c0.z + o[3] * c0.w +
                   o[4] * c1.x + o[5] * c1.y + o[6] * c1.z + o[7] * c1.w;
        for (int off = 8; off; off >>= 1) {
            pl += __shfl_xor(pl, off);
            pr += __shfl_xor(pr, off);
        }
        if (lane == 0) {
            al2_o[node] = make_float2(pl, disn);
            ar_o[node] = pr;
        }
    }
}

// ---------------- output: log_softmax(h @ W2^T + b2) ---------------------------
__global__ __launch_bounds__(256, 4) void k_out(const float* __restrict__ h,
                                                const float* __restrict__ W2,
                                                const float* __restrict__ b2,
                                                float* __restrict__ out, int n) {
    __shared__ float ws[NCLASS * LDSW];
    __shared__ float bs[NCLASS];
    const int tid = threadIdx.x;
    for (int i = tid; i < NCLASS * (HIDDEN / 4); i += 256) {
        int r = i >> 5;          // row (class), 32 float4 per row
        int c4 = i & 31;         // float4 index within row
        *(float4*)(ws + r * LDSW + c4 * 4) = ((const float4*)W2)[i];
    }
    if (tid < NCLASS) bs[tid] = b2[tid];
    __syncthreads();
    int node = blockIdx.x * 32 + (tid >> 3);
    const int ol = tid & 7;
    if (node >= n) return;
    const float* hr = h + (size_t)node * HIDDEN;
    float acc[5];
#pragma unroll
    for (int c = 0; c < 5; ++c) acc[c] = bs[ol + 8 * c];
#pragma unroll
    for (int k0 = 0; k0 < HIDDEN; k0 += 16) {
        float4 h0 = *(const float4*)(hr + k0);
        float4 h1 = *(const float4*)(hr + k0 + 4);
        float4 h2v = *(const float4*)(hr + k0 + 8);
        float4 h3 = *(const float4*)(hr + k0 + 12);
#pragma unroll
        for (int c = 0; c < 5; ++c) {
            const float* w = ws + (ol + 8 * c) * LDSW + k0;
            float4 w0 = *(const float4*)(w);
            float4 w1 = *(const float4*)(w + 4);
            float4 w2v = *(const float4*)(w + 8);
            float4 w3 = *(const float4*)(w + 12);
            acc[c] += h0.x * w0.x + h0.y * w0.y + h0.z * w0.z + h0.w * w0.w +
                      h1.x * w1.x + h1.y * w1.y + h1.z * w1.z + h1.w * w1.w +
                      h2v.x * w2v.x + h2v.y * w2v.y + h2v.z * w2v.z + h2v.w * w2v.w +
                      h3.x * w3.x + h3.y * w3.y + h3.z * w3.z + h3.w * w3.w;
        }
    }
    float m = acc[0];
#pragma unroll
    for (int c = 1; c < 5; ++c) m = fmaxf(m, acc[c]);
    m = fmaxf(m, __shfl_xor(m, 1));
    m = fmaxf(m, __shfl_xor(m, 2));
    m = fmaxf(m, __shfl_xor(m, 4));
    float ssum = 0.f;
#pragma unroll
    for (int c = 0; c < 5; ++c) ssum += expf(acc[c] - m);
    ssum += __shfl_xor(ssum, 1);
    ssum += __shfl_xor(ssum, 2);
    ssum += __shfl_xor(ssum, 4);
    float lse = m + logf(ssum);
    float* orow = out + (size_t)node * NCLASS;
#pragma unroll
    for (int c = 0; c < 5; ++c) orow[ol + 8 * c] = acc[c] - lse;
}

extern "C" void kernel_launch(void* const* d_in, const int* in_sizes, int n_in,
                              void* d_out, int out_size, void* d_ws, size_t ws_size,
                              hipStream_t stream) {
    const float* x    = (const float*)d_in[0];
    const int*   ei   = (const int*)d_in[1];
    const float* W1   = (const float*)d_in[2];
    const float* b1   = (const float*)d_in[3];
    const float* W2   = (const float*)d_in[4];
    const float* b2   = (const float*)d_in[5];
    const float* attl = (const float*)d_in[6];
    const float* attr = (const float*)d_in[7];
    const int N = in_sizes[0] / FEAT;
    const int E = in_sizes[1] / 2;
    float* out = (float*)d_out;

    char* p = (char*)d_ws;
    auto take = [&](size_t bytes) {
        void* q = (void*)p;
        p += (bytes + 255) & ~(size_t)255;
        return q;
    };
    float*    h0   = (float*)take((size_t)N * HIDDEN * 4);  // = raw
    float*    h1   = (float*)take((size_t)N * HIDDEN * 4);
    float*    h2   = (float*)take((size_t)N * HIDDEN * 4);
    unsigned* hb0  = (unsigned*)take((size_t)N * 64 * 4);
    unsigned* hb1  = (unsigned*)take((size_t)N * 64 * 4);
    int*      deg  = (int*)take((size_t)N * 4);
    float*    dis  = (float*)take((size_t)N * 4);
    int*      offs = (int*)take((size_t)(N + 1) * 4);
    unsigned* partial = (unsigned*)take((size_t)NB * PITCH * 4);
    ushort*   lrank   = (ushort*)take((size_t)E * 2);
    int*      csrc = (int*)take((size_t)E * 4);
    float2*   al2A = (float2*)take((size_t)N * 8);
    float2*   al2B = (float2*)take((size_t)N * 8);
    float*    arA  = (float*)take((size_t)N * 4);
    float*    arB  = (float*)take((size_t)N * 4);
    int*      part = (int*)take(1024);

    const int nbl = (N + 255) / 256;
    const int CE = (E + NB - 1) / NB;

    k_hist<<<NB, 256, 0, stream>>>(ei, E, CE, partial, lrank);
    k_hscan<<<(PITCH + 255) / 256, 256, 0, stream>>>(partial, deg, dis, N);
    k_scan1<<<nbl, 256, 0, stream>>>(deg, offs, part, N);
    k_scan2<<<1, 256, 0, stream>>>(part, nbl);
    k_scan3<<<nbl, 256, 0, stream>>>(offs, part, N, E);
    k_csr_fill<<<NB, 256, 0, stream>>>(ei, E, CE, offs, partial, lrank, csrc);

    k_gemm1<<<(N + BM1 - 1) / BM1, 256, 0, stream>>>(x, W1, b1, h0, N);
    k_prep<<<(N + 3) / 4, 256, 0, stream>>>(h0, hb0, attl, attr, dis, al2A, arA, N);

    float*    fout[4] = {h1, h2, h1, h2};
    unsigned* hbin = hb0, *hbout = hb1;
    float2*   alin = al2A, *alout = al2B;
    float*    arin = arA,  *arout = arB;
    for (int l = 0; l < 4; ++l) {
        const float* attl_n = (l < 3) ? (attl + (l + 1) * HIDDEN) : nullptr;
        const float* attr_n = (l < 3) ? (attr + (l + 1) * HIDDEN) : nullptr;
        unsigned* hbo = (l < 3) ? hbout : nullptr;
        k_aggregate<<<(N + 3) / 4, 256, 0, stream>>>(hbin, h0, alin, arin, offs, csrc,
                                                     fout[l], hbo, attl_n, attr_n,
                                                     alout, arout, N);
        unsigned* tb = hbin; hbin = hbout; hbout = tb;
        float2* ta = alin; alin = alout; alout = ta;
        float* tr = arin; arin = arout; arout = tr;
    }

    k_out<<<(N + 31) / 32, 256, 0, stream>>>(h2, W2, b2, out, N);
}

// Round 9
// 514.054 us; speedup vs baseline: 1.2573x; 1.0058x over previous
//
#include <hip/hip_runtime.h>
#include <cmath>

// FAGCN: N=50000, E=1.6M, FEAT=512, HIDDEN=128, CLASS=40, 4 layers, eps=0.3
// R18: dead-write elimination — layers 0-2 of k_aggregate wrote a 25.6MB f32
// hout that nothing ever reads (next layer consumes the bf16 copy + raw=h0;
// only layer 3's f32 output feeds k_out). hout write now conditional; launcher
// passes hout=nullptr for l<3, houtbf=nullptr for l=3. Saves 77MB of HBM
// writes. R17 post-mortem: packed FMA was NULL on duration (62.4us, VALU
// 52->49, VGPR 36->28) => aggregate is bytes/BW-bound (224MB @ 3.57 TB/s =
// 62.5us exactly). Prediction: agg l<3 dur 62.4 -> ~56 (198MB), total ~495.

#define HIDDEN 128
#define FEAT 512
#define NCLASS 40
#define LDST 40    // GEMM LDS row stride in ushorts (80 B)
#define LDSW 132   // k_out ws row stride in floats (528 B -> 4-bank shift/row)
#define NB 256     // histogram chunks (= blocks)
#define PITCH 12544  // words per partial row: 4 nodes/word -> supports N<=50176
#define BM1 64     // k_gemm1 M-tile

typedef __attribute__((ext_vector_type(8))) short short8;
typedef __attribute__((ext_vector_type(4))) float f32x4;
typedef __attribute__((ext_vector_type(2))) float f32x2;

__device__ __forceinline__ float bf_lo(unsigned u) { return __uint_as_float(u << 16); }
__device__ __forceinline__ float bf_hi(unsigned u) { return __uint_as_float(u & 0xffff0000u); }
__device__ __forceinline__ f32x2 up2(unsigned u) {
    f32x2 v; v.x = bf_lo(u); v.y = bf_hi(u); return v;
}
__device__ __forceinline__ unsigned pack_bf16(float x, float y) {
    unsigned ux = __float_as_uint(x);
    unsigned uy = __float_as_uint(y);
    unsigned lx = (ux + 0x7fffu + ((ux >> 16) & 1u)) >> 16;
    unsigned hy = (uy + 0x7fffu + ((uy >> 16) & 1u)) & 0xffff0000u;
    return hy | lx;
}
__device__ __forceinline__ float fast_tanh(float x) {
    x = fminf(fmaxf(x, -15.f), 15.f);
    float e = __expf(2.f * x);
    return (e - 1.f) / (e + 1.f);
}

// packed accumulate: 4x v_pk_fma_f32 per uint4
#define ACC4P(c, r) { f32x2 c2; c2.x = c; c2.y = c; \
    acc2[0] = __builtin_elementwise_fma(c2, up2(r.x), acc2[0]); \
    acc2[1] = __builtin_elementwise_fma(c2, up2(r.y), acc2[1]); \
    acc2[2] = __builtin_elementwise_fma(c2, up2(r.z), acc2[2]); \
    acc2[3] = __builtin_elementwise_fma(c2, up2(r.w), acc2[3]); }

// ---------------- per-chunk LDS histogram (8-bit packed) + local rank ----------
__global__ __launch_bounds__(256) void k_hist(const int* __restrict__ ei, int E, int CE,
                                              unsigned* __restrict__ partial,
                                              ushort* __restrict__ lrank) {
    __shared__ unsigned lh[PITCH];
    const int b = blockIdx.x, tid = threadIdx.x;
    for (int w = tid; w < PITCH; w += 256) lh[w] = 0;
    __syncthreads();
    int e0 = b * CE, e1 = min(E, e0 + CE);
    for (int e = e0 + tid; e < e1; e += 256) {
        int dst = ei[E + e];
        int sh = (dst & 3) * 8;
        unsigned old = atomicAdd(&lh[dst >> 2], 1u << sh);
        lrank[e] = (ushort)((old >> sh) & 0xffu);
    }
    __syncthreads();
    unsigned* prow = partial + (size_t)b * PITCH;
    for (int w = tid; w < PITCH; w += 256) prow[w] = lh[w];
}

// ---------------- cross-chunk exclusive scan (in place) + degree + dis ---------
__global__ __launch_bounds__(256) void k_hscan(unsigned* __restrict__ partial,
                                               int* __restrict__ deg,
                                               float* __restrict__ dis, int n) {
    int w = blockIdx.x * 256 + threadIdx.x;
    if (w >= PITCH) return;
    unsigned run = 0;
    size_t idx = w;
    for (int b = 0; b < NB; ++b, idx += PITCH) {
        unsigned v = partial[idx];
        partial[idx] = run;
        run += v;
    }
    int node = 4 * w;
    int d0 = run & 0xffu, d1 = (run >> 8) & 0xffu, d2 = (run >> 16) & 0xffu, d3 = run >> 24;
    if (node < n)     { deg[node]     = d0; dis[node]     = rsqrtf((float)(d0 + 1)); }
    if (node + 1 < n) { deg[node + 1] = d1; dis[node + 1] = rsqrtf((float)(d1 + 1)); }
    if (node + 2 < n) { deg[node + 2] = d2; dis[node + 2] = rsqrtf((float)(d2 + 1)); }
    if (node + 3 < n) { deg[node + 3] = d3; dis[node + 3] = rsqrtf((float)(d3 + 1)); }
}

// ---------------- exclusive scan over node degrees (offs) ----------------
__global__ __launch_bounds__(256) void k_scan1(const int* __restrict__ deg, int* __restrict__ offs,
                                               int* __restrict__ part, int n) {
    __shared__ int s[256];
    int tid = threadIdx.x;
    int gid = blockIdx.x * 256 + tid;
    int v = (gid < n) ? deg[gid] : 0;
    s[tid] = v;
    __syncthreads();
    for (int off = 1; off < 256; off <<= 1) {
        int t = (tid >= off) ? s[tid - off] : 0;
        __syncthreads();
        s[tid] += t;
        __syncthreads();
    }
    if (gid < n) offs[gid] = s[tid] - v;
    if (tid == 255) part[blockIdx.x] = s[255];
}

__global__ __launch_bounds__(256) void k_scan2(int* __restrict__ part, int nb) {
    __shared__ int s[256];
    int tid = threadIdx.x;
    int v = (tid < nb) ? part[tid] : 0;
    s[tid] = v;
    __syncthreads();
    for (int off = 1; off < 256; off <<= 1) {
        int t = (tid >= off) ? s[tid - off] : 0;
        __syncthreads();
        s[tid] += t;
        __syncthreads();
    }
    if (tid < nb) part[tid] = s[tid] - v;
}

__global__ __launch_bounds__(256) void k_scan3(int* __restrict__ offs, const int* __restrict__ part,
                                               int n, int E) {
    int gid = blockIdx.x * 256 + threadIdx.x;
    if (gid < n) offs[gid] += part[blockIdx.x];
    if (gid == 0) offs[n] = E;
}

// ---------------- CSR fill: no atomics; chunk base row staged in LDS -----------
__global__ __launch_bounds__(256) void k_csr_fill(const int* __restrict__ ei, int E, int CE,
                                                  const int* __restrict__ offs,
                                                  const unsigned* __restrict__ partial,
                                                  const ushort* __restrict__ lrank,
                                                  int* __restrict__ csrc) {
    __shared__ unsigned lp[PITCH];
    const int b = blockIdx.x, tid = threadIdx.x;
    const unsigned* prow = partial + (size_t)b * PITCH;
    for (int w = tid; w < PITCH; w += 256) lp[w] = prow[w];
    __syncthreads();
    int e0 = b * CE, e1 = min(E, e0 + CE);
    for (int e = e0 + tid; e < e1; e += 256) {
        int dst = ei[E + e];
        int src = ei[e];
        unsigned wv = lp[dst >> 2];
        int base = (wv >> ((dst & 3) * 8)) & 0xffu;
        csrc[offs[dst] + base + (int)lrank[e]] = src;
    }
}

// ---------------- GEMM1: h = relu(x @ W1^T + b1), MFMA bf16 -------------------
__global__ __launch_bounds__(256) void k_gemm1(const float* __restrict__ x,
                                               const float* __restrict__ W1,
                                               const float* __restrict__ b1,
                                               float* __restrict__ h, int M) {
    __shared__ ushort As[BM1 * LDST];
    __shared__ ushort Bs[128 * LDST];
    const int tid = threadIdx.x;
    const int bm = blockIdx.x * BM1;
    const int wave = tid >> 6, lane = tid & 63;
    const int rh = (wave >> 1) * 32;   // wave row offset: 0 / 32
    const int ch = (wave & 1) * 64;    // wave col offset: 0 / 64
    const int sub = lane & 15, quad = lane >> 4;
    const int lrow = tid >> 3;         // 0..31
    const int lcol = (tid & 7) * 4;    // 0..28
    f32x4 acc[2][4] = {};
    float4 av[2], bv[4];
    // prologue: load K-tile 0 into registers
#pragma unroll
    for (int i = 0; i < 2; ++i) {
        int grow = bm + lrow + 32 * i;
        av[i] = (grow < M) ? *(const float4*)(x + (size_t)grow * FEAT + lcol)
                           : make_float4(0.f, 0.f, 0.f, 0.f);
    }
#pragma unroll
    for (int i = 0; i < 4; ++i)
        bv[i] = *(const float4*)(W1 + (size_t)(lrow + 32 * i) * FEAT + lcol);

    for (int k0 = 0; k0 < FEAT; k0 += 32) {
        // stage current tile regs -> LDS (bf16 pack)
#pragma unroll
        for (int i = 0; i < 2; ++i)
            *(uint2*)(As + (lrow + 32 * i) * LDST + lcol) =
                make_uint2(pack_bf16(av[i].x, av[i].y), pack_bf16(av[i].z, av[i].w));
#pragma unroll
        for (int i = 0; i < 4; ++i)
            *(uint2*)(Bs + (lrow + 32 * i) * LDST + lcol) =
                make_uint2(pack_bf16(bv[i].x, bv[i].y), pack_bf16(bv[i].z, bv[i].w));
        __syncthreads();
        // prefetch next K-tile into registers (overlaps ds_read + MFMA below)
        if (k0 + 32 < FEAT) {
            const int kn = k0 + 32;
#pragma unroll
            for (int i = 0; i < 2; ++i) {
                int grow = bm + lrow + 32 * i;
                av[i] = (grow < M) ? *(const float4*)(x + (size_t)grow * FEAT + kn + lcol)
                                   : make_float4(0.f, 0.f, 0.f, 0.f);
            }
#pragma unroll
            for (int i = 0; i < 4; ++i)
                bv[i] = *(const float4*)(W1 + (size_t)(lrow + 32 * i) * FEAT + kn + lcol);
        }
        short8 af[2], bfr[4];
#pragma unroll
        for (int t = 0; t < 2; ++t)
            af[t] = *(const short8*)(As + (rh + t * 16 + sub) * LDST + quad * 8);
#pragma unroll
        for (int u = 0; u < 4; ++u)
            bfr[u] = *(const short8*)(Bs + (ch + u * 16 + sub) * LDST + quad * 8);
#pragma unroll
        for (int t = 0; t < 2; ++t)
#pragma unroll
            for (int u = 0; u < 4; ++u)
                acc[t][u] = __builtin_amdgcn_mfma_f32_16x16x32_bf16(af[t], bfr[u], acc[t][u], 0, 0, 0);
        __syncthreads();
    }
    float b1v[4];
#pragma unroll
    for (int u = 0; u < 4; ++u) b1v[u] = b1[ch + u * 16 + sub];
#pragma unroll
    for (int t = 0; t < 2; ++t) {
#pragma unroll
        for (int u = 0; u < 4; ++u) {
            int col = ch + u * 16 + sub;
#pragma unroll
            for (int r2 = 0; r2 < 4; ++r2) {
                int grow = bm + rh + t * 16 + quad * 4 + r2;
                if (grow < M)
                    h[(size_t)grow * HIDDEN + col] = fmaxf(acc[t][u][r2] + b1v[u], 0.f);
            }
        }
    }
}

// ---------------- prep: bf16 pack + layer-0 dots -> {al,dis}, ar ----------------
__global__ __launch_bounds__(256) void k_prep(const float* __restrict__ h, unsigned* __restrict__ hbf,
                       const float* __restrict__ attl, const float* __restrict__ attr,
                       const float* __restrict__ dis, float2* __restrict__ al2,
                       float* __restrict__ ar, int n) {
    int node = (blockIdx.x * blockDim.x + threadIdx.x) >> 6;
    int lane = threadIdx.x & 63;
    if (node >= n) return;
    float2 hv = ((const float2*)(h + (size_t)node * HIDDEN))[lane];
    hbf[(size_t)node * 64 + lane] = pack_bf16(hv.x, hv.y);
    float pl = hv.x * attl[2 * lane] + hv.y * attl[2 * lane + 1];
    float pr = hv.x * attr[2 * lane] + hv.y * attr[2 * lane + 1];
    for (int off = 32; off; off >>= 1) {
        pl += __shfl_down(pl, off);
        pr += __shfl_down(pr, off);
    }
    if (lane == 0) {
        al2[node] = make_float2(pl, dis[node]);
        ar[node] = pr;
    }
}

// ---------------- aggregate: phase-1 coef batch + packed-FMA hot loop ----------
// hout (f32) written only when non-null: layers 0-2 emit bf16 only (their f32
// output is dead — next layer reads hbf + raw), layer 3 emits f32 only.
__global__ __launch_bounds__(256) void k_aggregate(
                            const unsigned* __restrict__ hbf, const float* __restrict__ raw,
                            const float2* __restrict__ al2, const float* __restrict__ ar,
                            const int* __restrict__ offs, const int* __restrict__ csrc,
                            float* __restrict__ hout, unsigned* __restrict__ houtbf,
                            const float* __restrict__ attl_n, const float* __restrict__ attr_n,
                            float2* __restrict__ al2_o, float* __restrict__ ar_o, int n) {
    int node = (blockIdx.x * blockDim.x + threadIdx.x) >> 6;
    int lane = threadIdx.x & 63;
    if (node >= n) return;
    const int grp = lane >> 4;
    const int sub = lane & 15;
    const float arn = ar[node];
    const float2 selfld = al2[node];
    const float disn = selfld.y;
    f32x2 acc2[4] = {};
    int e0 = offs[node], e1 = offs[node + 1];
    for (int base = e0; base < e1; base += 64) {
        int cnt = min(64, e1 - base);
        // phase 1: one coef per lane (zero-padded past cnt)
        int idx = base + lane;
        int smy = (lane < cnt) ? csrc[idx] : node;
        float2 lmy = al2[smy];
        float cmy = (lane < cnt) ? fast_tanh(lmy.x + arn) * lmy.y * disn : 0.f;
        // phase 2: 16-edge hot loop, src/coef via shfl, packed FMA
        int t = 0;
        for (; t + 16 <= cnt; t += 16) {
            int sa = __shfl(smy, t + grp);
            int sb = __shfl(smy, t + 4 + grp);
            int sc = __shfl(smy, t + 8 + grp);
            int sd = __shfl(smy, t + 12 + grp);
            float ca = __shfl(cmy, t + grp);
            float cb = __shfl(cmy, t + 4 + grp);
            float cc = __shfl(cmy, t + 8 + grp);
            float cd = __shfl(cmy, t + 12 + grp);
            uint4 ra = *(const uint4*)(hbf + (size_t)sa * 64 + sub * 4);
            uint4 rb = *(const uint4*)(hbf + (size_t)sb * 64 + sub * 4);
            uint4 rc = *(const uint4*)(hbf + (size_t)sc * 64 + sub * 4);
            uint4 rd = *(const uint4*)(hbf + (size_t)sd * 64 + sub * 4);
            ACC4P(ca, ra); ACC4P(cb, rb); ACC4P(cc, rc); ACC4P(cd, rd);
        }
        for (; t < cnt; t += 4) {   // zero-padded tail (covers 1-3 leftovers too)
            int sa = __shfl(smy, t + grp);
            float ca = __shfl(cmy, t + grp);
            uint4 ra = *(const uint4*)(hbf + (size_t)sa * 64 + sub * 4);
            ACC4P(ca, ra);
        }
    }
#pragma unroll
    for (int j = 0; j < 4; ++j) {
        acc2[j].x += __shfl_xor(acc2[j].x, 16);
        acc2[j].y += __shfl_xor(acc2[j].y, 16);
        acc2[j].x += __shfl_xor(acc2[j].x, 32);
        acc2[j].y += __shfl_xor(acc2[j].y, 32);
    }
    {   // self-loop term (post-reduce, replicated across groups)
        float c = fast_tanh(selfld.x + arn) * disn * disn;
        uint4 r = *(const uint4*)(hbf + (size_t)node * 64 + sub * 4);
        ACC4P(c, r);
    }
    float o[8];
    {
        float4 rv0 = *(const float4*)(raw + (size_t)node * HIDDEN + sub * 8);
        float4 rv1 = *(const float4*)(raw + (size_t)node * HIDDEN + sub * 8 + 4);
        o[0] = acc2[0].x + 0.3f * rv0.x; o[1] = acc2[0].y + 0.3f * rv0.y;
        o[2] = acc2[1].x + 0.3f * rv0.z; o[3] = acc2[1].y + 0.3f * rv0.w;
        o[4] = acc2[2].x + 0.3f * rv1.x; o[5] = acc2[2].y + 0.3f * rv1.y;
        o[6] = acc2[3].x + 0.3f * rv1.z; o[7] = acc2[3].y + 0.3f * rv1.w;
    }
    if (grp == 0) {
        if (hout) {
            *(float4*)(hout + (size_t)node * HIDDEN + sub * 8) = make_float4(o[0], o[1], o[2], o[3]);
            *(float4*)(hout + (size_t)node * HIDDEN + sub * 8 + 4) = make_float4(o[4], o[5], o[6], o[7]);
        }
        if (houtbf) {
            uint4 pk = make_uint4(pack_bf16(o[0], o[1]), pack_bf16(o[2], o[3]),
                                  pack_bf16(o[4], o[5]), pack_bf16(o[6], o[7]));
            *(uint4*)(houtbf + (size_t)node * 64 + sub * 4) = pk;
        }
    }
    if (attl_n) {
        float4 a0 = *(const float4*)(attl_n + sub * 8);
        float4 a1 = *(const float4*)(attl_n + sub * 8 + 4);
        float4 c0 = *(const float4*)(attr_n + sub * 8);
        float4 c1 = *(const float4*)(attr_n + sub * 8 + 4);
        float pl = o[0] * a0.x + o[1] * a0.y + o[2] * a0.z + o[3] * a0.w +
                   o[4] * a1.x + o[5] * a1.y + o[6] * a1.z + o[7] * a1.w;
        float pr = o[0] * c0.x + o[1] * c0.y + o[2] * c0.z + o[3] * c0.w +
                   o[4] * c1.x + o[5] * c1.y + o[6] * c1.z + o[7] * c1.w;
        for (int off = 8; off; off >>= 1) {
            pl += __shfl_xor(pl, off);
            pr += __shfl_xor(pr, off);
        }
        if (lane == 0) {
            al2_o[node] = make_float2(pl, disn);
            ar_o[node] = pr;
        }
    }
}

// ---------------- output: log_softmax(h @ W2^T + b2) ---------------------------
__global__ __launch_bounds__(256, 4) void k_out(const float* __restrict__ h,
                                                const float* __restrict__ W2,
                                                const float* __restrict__ b2,
                                                float* __restrict__ out, int n) {
    __shared__ float ws[NCLASS * LDSW];
    __shared__ float bs[NCLASS];
    const int tid = threadIdx.x;
    for (int i = tid; i < NCLASS * (HIDDEN / 4); i += 256) {
        int r = i >> 5;          // row (class), 32 float4 per row
        int c4 = i & 31;         // float4 index within row
        *(float4*)(ws + r * LDSW + c4 * 4) = ((const float4*)W2)[i];
    }
    if (tid < NCLASS) bs[tid] = b2[tid];
    __syncthreads();
    int node = blockIdx.x * 32 + (tid >> 3);
    const int ol = tid & 7;
    if (node >= n) return;
    const float* hr = h + (size_t)node * HIDDEN;
    float acc[5];
#pragma unroll
    for (int c = 0; c < 5; ++c) acc[c] = bs[ol + 8 * c];
#pragma unroll
    for (int k0 = 0; k0 < HIDDEN; k0 += 16) {
        float4 h0 = *(const float4*)(hr + k0);
        float4 h1 = *(const float4*)(hr + k0 + 4);
        float4 h2v = *(const float4*)(hr + k0 + 8);
        float4 h3 = *(const float4*)(hr + k0 + 12);
#pragma unroll
        for (int c = 0; c < 5; ++c) {
            const float* w = ws + (ol + 8 * c) * LDSW + k0;
            float4 w0 = *(const float4*)(w);
            float4 w1 = *(const float4*)(w + 4);
            float4 w2v = *(const float4*)(w + 8);
            float4 w3 = *(const float4*)(w + 12);
            acc[c] += h0.x * w0.x + h0.y * w0.y + h0.z * w0.z + h0.w * w0.w +
                      h1.x * w1.x + h1.y * w1.y + h1.z * w1.z + h1.w * w1.w +
                      h2v.x * w2v.x + h2v.y * w2v.y + h2v.z * w2v.z + h2v.w * w2v.w +
                      h3.x * w3.x + h3.y * w3.y + h3.z * w3.z + h3.w * w3.w;
        }
    }
    float m = acc[0];
#pragma unroll
    for (int c = 1; c < 5; ++c) m = fmaxf(m, acc[c]);
    m = fmaxf(m, __shfl_xor(m, 1));
    m = fmaxf(m, __shfl_xor(m, 2));
    m = fmaxf(m, __shfl_xor(m, 4));
    float ssum = 0.f;
#pragma unroll
    for (int c = 0; c < 5; ++c) ssum += expf(acc[c] - m);
    ssum += __shfl_xor(ssum, 1);
    ssum += __shfl_xor(ssum, 2);
    ssum += __shfl_xor(ssum, 4);
    float lse = m + logf(ssum);
    float* orow = out + (size_t)node * NCLASS;
#pragma unroll
    for (int c = 0; c < 5; ++c) orow[ol + 8 * c] = acc[c] - lse;
}

extern "C" void kernel_launch(void* const* d_in, const int* in_sizes, int n_in,
                              void* d_out, int out_size, void* d_ws, size_t ws_size,
                              hipStream_t stream) {
    const float* x    = (const float*)d_in[0];
    const int*   ei   = (const int*)d_in[1];
    const float* W1   = (const float*)d_in[2];
    const float* b1   = (const float*)d_in[3];
    const float* W2   = (const float*)d_in[4];
    const float* b2   = (const float*)d_in[5];
    const float* attl = (const float*)d_in[6];
    const float* attr = (const float*)d_in[7];
    const int N = in_sizes[0] / FEAT;
    const int E = in_sizes[1] / 2;
    float* out = (float*)d_out;

    char* p = (char*)d_ws;
    auto take = [&](size_t bytes) {
        void* q = (void*)p;
        p += (bytes + 255) & ~(size_t)255;
        return q;
    };
    float*    h0   = (float*)take((size_t)N * HIDDEN * 4);  // = raw
    float*    h2   = (float*)take((size_t)N * HIDDEN * 4);  // layer-3 f32 output
    unsigned* hb0  = (unsigned*)take((size_t)N * 64 * 4);
    unsigned* hb1  = (unsigned*)take((size_t)N * 64 * 4);
    int*      deg  = (int*)take((size_t)N * 4);
    float*    dis  = (float*)take((size_t)N * 4);
    int*      offs = (int*)take((size_t)(N + 1) * 4);
    unsigned* partial = (unsigned*)take((size_t)NB * PITCH * 4);
    ushort*   lrank   = (ushort*)take((size_t)E * 2);
    int*      csrc = (int*)take((size_t)E * 4);
    float2*   al2A = (float2*)take((size_t)N * 8);
    float2*   al2B = (float2*)take((size_t)N * 8);
    float*    arA  = (float*)take((size_t)N * 4);
    float*    arB  = (float*)take((size_t)N * 4);
    int*      part = (int*)take(1024);

    const int nbl = (N + 255) / 256;
    const int CE = (E + NB - 1) / NB;

    k_hist<<<NB, 256, 0, stream>>>(ei, E, CE, partial, lrank);
    k_hscan<<<(PITCH + 255) / 256, 256, 0, stream>>>(partial, deg, dis, N);
    k_scan1<<<nbl, 256, 0, stream>>>(deg, offs, part, N);
    k_scan2<<<1, 256, 0, stream>>>(part, nbl);
    k_scan3<<<nbl, 256, 0, stream>>>(offs, part, N, E);
    k_csr_fill<<<NB, 256, 0, stream>>>(ei, E, CE, offs, partial, lrank, csrc);

    k_gemm1<<<(N + BM1 - 1) / BM1, 256, 0, stream>>>(x, W1, b1, h0, N);
    k_prep<<<(N + 3) / 4, 256, 0, stream>>>(h0, hb0, attl, attr, dis, al2A, arA, N);

    unsigned* hbin = hb0, *hbout = hb1;
    float2*   alin = al2A, *alout = al2B;
    float*    arin = arA,  *arout = arB;
    for (int l = 0; l < 4; ++l) {
        const bool last = (l == 3);
        const float* attl_n = (!last) ? (attl + (l + 1) * HIDDEN) : nullptr;
        const float* attr_n = (!last) ? (attr + (l + 1) * HIDDEN) : nullptr;
        float*    fo  = last ? h2 : nullptr;       // f32 out only for final layer
        unsigned* hbo = last ? nullptr : hbout;    // bf16 out only for l<3
        k_aggregate<<<(N + 3) / 4, 256, 0, stream>>>(hbin, h0, alin, arin, offs, csrc,
                                                     fo, hbo, attl_n, attr_n,
                                                     alout, arout, N);
        unsigned* tb = hbin; hbin = hbout; hbout = tb;
        float2* ta = alin; alin = alout; alout = ta;
        float* tr = arin; arin = arout; arout = tr;
    }

    k_out<<<(N + 31) / 32, 256, 0, stream>>>(h2, W2, b2, out, N);
}

// Round 11
// 513.687 us; speedup vs baseline: 1.2582x; 1.0007x over previous
//
#include <hip/hip_runtime.h>
#include <cmath>

// FAGCN: N=50000, E=1.6M, FEAT=512, HIDDEN=128, CLASS=40, 4 layers, eps=0.3
// R20 = R19 resubmitted verbatim (R19 bench failed on container infra, never
// measured). k_prep fused into k_gemm1 (k_gemm1p) — epilogue stages relu'd h
// tile in LDS (hs[64][129], total LDS 48KB -> 3 blocks/CU at grid 782), then
// each wave preps 16 nodes from LDS (bf16 pack -> hbf, att dots -> al2/ar).
// Deletes k_prep's 25.6MB h re-read + one dispatch. Bit-identical numerics.
// R18 post-mortem: write elimination was -3us only — writes are off the
// critical path; agg is FETCH-bound (~180MB random-line @ ~2.9 TB/s,
// structural). CSR build measured ~15us total (R13/R14 A/B). Remaining
// attackable: duplicate data movement + dispatch count.

#define HIDDEN 128
#define FEAT 512
#define NCLASS 40
#define LDST 40    // GEMM LDS row stride in ushorts (80 B)
#define LDSW 132   // k_out ws row stride in floats (528 B -> 4-bank shift/row)
#define NB 256     // histogram chunks (= blocks)
#define PITCH 12544  // words per partial row: 4 nodes/word -> supports N<=50176
#define BM1 64     // k_gemm1 M-tile

typedef __attribute__((ext_vector_type(8))) short short8;
typedef __attribute__((ext_vector_type(4))) float f32x4;
typedef __attribute__((ext_vector_type(2))) float f32x2;

__device__ __forceinline__ float bf_lo(unsigned u) { return __uint_as_float(u << 16); }
__device__ __forceinline__ float bf_hi(unsigned u) { return __uint_as_float(u & 0xffff0000u); }
__device__ __forceinline__ f32x2 up2(unsigned u) {
    f32x2 v; v.x = bf_lo(u); v.y = bf_hi(u); return v;
}
__device__ __forceinline__ unsigned pack_bf16(float x, float y) {
    unsigned ux = __float_as_uint(x);
    unsigned uy = __float_as_uint(y);
    unsigned lx = (ux + 0x7fffu + ((ux >> 16) & 1u)) >> 16;
    unsigned hy = (uy + 0x7fffu + ((uy >> 16) & 1u)) & 0xffff0000u;
    return hy | lx;
}
__device__ __forceinline__ float fast_tanh(float x) {
    x = fminf(fmaxf(x, -15.f), 15.f);
    float e = __expf(2.f * x);
    return (e - 1.f) / (e + 1.f);
}

// packed accumulate: 4x v_pk_fma_f32 per uint4
#define ACC4P(c, r) { f32x2 c2; c2.x = c; c2.y = c; \
    acc2[0] = __builtin_elementwise_fma(c2, up2(r.x), acc2[0]); \
    acc2[1] = __builtin_elementwise_fma(c2, up2(r.y), acc2[1]); \
    acc2[2] = __builtin_elementwise_fma(c2, up2(r.z), acc2[2]); \
    acc2[3] = __builtin_elementwise_fma(c2, up2(r.w), acc2[3]); }

// ---------------- per-chunk LDS histogram (8-bit packed) + local rank ----------
__global__ __launch_bounds__(256) void k_hist(const int* __restrict__ ei, int E, int CE,
                                              unsigned* __restrict__ partial,
                                              ushort* __restrict__ lrank) {
    __shared__ unsigned lh[PITCH];
    const int b = blockIdx.x, tid = threadIdx.x;
    for (int w = tid; w < PITCH; w += 256) lh[w] = 0;
    __syncthreads();
    int e0 = b * CE, e1 = min(E, e0 + CE);
    for (int e = e0 + tid; e < e1; e += 256) {
        int dst = ei[E + e];
        int sh = (dst & 3) * 8;
        unsigned old = atomicAdd(&lh[dst >> 2], 1u << sh);
        lrank[e] = (ushort)((old >> sh) & 0xffu);
    }
    __syncthreads();
    unsigned* prow = partial + (size_t)b * PITCH;
    for (int w = tid; w < PITCH; w += 256) prow[w] = lh[w];
}

// ---------------- cross-chunk exclusive scan (in place) + degree + dis ---------
__global__ __launch_bounds__(256) void k_hscan(unsigned* __restrict__ partial,
                                               int* __restrict__ deg,
                                               float* __restrict__ dis, int n) {
    int w = blockIdx.x * 256 + threadIdx.x;
    if (w >= PITCH) return;
    unsigned run = 0;
    size_t idx = w;
    for (int b = 0; b < NB; ++b, idx += PITCH) {
        unsigned v = partial[idx];
        partial[idx] = run;
        run += v;
    }
    int node = 4 * w;
    int d0 = run & 0xffu, d1 = (run >> 8) & 0xffu, d2 = (run >> 16) & 0xffu, d3 = run >> 24;
    if (node < n)     { deg[node]     = d0; dis[node]     = rsqrtf((float)(d0 + 1)); }
    if (node + 1 < n) { deg[node + 1] = d1; dis[node + 1] = rsqrtf((float)(d1 + 1)); }
    if (node + 2 < n) { deg[node + 2] = d2; dis[node + 2] = rsqrtf((float)(d2 + 1)); }
    if (node + 3 < n) { deg[node + 3] = d3; dis[node + 3] = rsqrtf((float)(d3 + 1)); }
}

// ---------------- exclusive scan over node degrees (offs) ----------------
__global__ __launch_bounds__(256) void k_scan1(const int* __restrict__ deg, int* __restrict__ offs,
                                               int* __restrict__ part, int n) {
    __shared__ int s[256];
    int tid = threadIdx.x;
    int gid = blockIdx.x * 256 + tid;
    int v = (gid < n) ? deg[gid] : 0;
    s[tid] = v;
    __syncthreads();
    for (int off = 1; off < 256; off <<= 1) {
        int t = (tid >= off) ? s[tid - off] : 0;
        __syncthreads();
        s[tid] += t;
        __syncthreads();
    }
    if (gid < n) offs[gid] = s[tid] - v;
    if (tid == 255) part[blockIdx.x] = s[255];
}

__global__ __launch_bounds__(256) void k_scan2(int* __restrict__ part, int nb) {
    __shared__ int s[256];
    int tid = threadIdx.x;
    int v = (tid < nb) ? part[tid] : 0;
    s[tid] = v;
    __syncthreads();
    for (int off = 1; off < 256; off <<= 1) {
        int t = (tid >= off) ? s[tid - off] : 0;
        __syncthreads();
        s[tid] += t;
        __syncthreads();
    }
    if (tid < nb) part[tid] = s[tid] - v;
}

__global__ __launch_bounds__(256) void k_scan3(int* __restrict__ offs, const int* __restrict__ part,
                                               int n, int E) {
    int gid = blockIdx.x * 256 + threadIdx.x;
    if (gid < n) offs[gid] += part[blockIdx.x];
    if (gid == 0) offs[n] = E;
}

// ---------------- CSR fill: no atomics; chunk base row staged in LDS -----------
__global__ __launch_bounds__(256) void k_csr_fill(const int* __restrict__ ei, int E, int CE,
                                                  const int* __restrict__ offs,
                                                  const unsigned* __restrict__ partial,
                                                  const ushort* __restrict__ lrank,
                                                  int* __restrict__ csrc) {
    __shared__ unsigned lp[PITCH];
    const int b = blockIdx.x, tid = threadIdx.x;
    const unsigned* prow = partial + (size_t)b * PITCH;
    for (int w = tid; w < PITCH; w += 256) lp[w] = prow[w];
    __syncthreads();
    int e0 = b * CE, e1 = min(E, e0 + CE);
    for (int e = e0 + tid; e < e1; e += 256) {
        int dst = ei[E + e];
        int src = ei[e];
        unsigned wv = lp[dst >> 2];
        int base = (wv >> ((dst & 3) * 8)) & 0xffu;
        csrc[offs[dst] + base + (int)lrank[e]] = src;
    }
}

// ---------------- GEMM1 + fused prep: h = relu(x@W1^T+b1); hbf/al2/ar ----------
__global__ __launch_bounds__(256) void k_gemm1p(const float* __restrict__ x,
                                                const float* __restrict__ W1,
                                                const float* __restrict__ b1,
                                                float* __restrict__ h,
                                                unsigned* __restrict__ hbf,
                                                const float* __restrict__ attl,
                                                const float* __restrict__ attr,
                                                const float* __restrict__ dis,
                                                float2* __restrict__ al2,
                                                float* __restrict__ ar_out, int M) {
    __shared__ ushort As[BM1 * LDST];
    __shared__ ushort Bs[128 * LDST];
    __shared__ float hs[BM1][HIDDEN + 1];   // relu'd tile for fused prep
    const int tid = threadIdx.x;
    const int bm = blockIdx.x * BM1;
    const int wave = tid >> 6, lane = tid & 63;
    const int rh = (wave >> 1) * 32;   // wave row offset: 0 / 32
    const int ch = (wave & 1) * 64;    // wave col offset: 0 / 64
    const int sub = lane & 15, quad = lane >> 4;
    const int lrow = tid >> 3;         // 0..31
    const int lcol = (tid & 7) * 4;    // 0..28
    f32x4 acc[2][4] = {};
    float4 av[2], bv[4];
    // prologue: load K-tile 0 into registers
#pragma unroll
    for (int i = 0; i < 2; ++i) {
        int grow = bm + lrow + 32 * i;
        av[i] = (grow < M) ? *(const float4*)(x + (size_t)grow * FEAT + lcol)
                           : make_float4(0.f, 0.f, 0.f, 0.f);
    }
#pragma unroll
    for (int i = 0; i < 4; ++i)
        bv[i] = *(const float4*)(W1 + (size_t)(lrow + 32 * i) * FEAT + lcol);

    for (int k0 = 0; k0 < FEAT; k0 += 32) {
        // stage current tile regs -> LDS (bf16 pack)
#pragma unroll
        for (int i = 0; i < 2; ++i)
            *(uint2*)(As + (lrow + 32 * i) * LDST + lcol) =
                make_uint2(pack_bf16(av[i].x, av[i].y), pack_bf16(av[i].z, av[i].w));
#pragma unroll
        for (int i = 0; i < 4; ++i)
            *(uint2*)(Bs + (lrow + 32 * i) * LDST + lcol) =
                make_uint2(pack_bf16(bv[i].x, bv[i].y), pack_bf16(bv[i].z, bv[i].w));
        __syncthreads();
        // prefetch next K-tile into registers (overlaps ds_read + MFMA below)
        if (k0 + 32 < FEAT) {
            const int kn = k0 + 32;
#pragma unroll
            for (int i = 0; i < 2; ++i) {
                int grow = bm + lrow + 32 * i;
                av[i] = (grow < M) ? *(const float4*)(x + (size_t)grow * FEAT + kn + lcol)
                                   : make_float4(0.f, 0.f, 0.f, 0.f);
            }
#pragma unroll
            for (int i = 0; i < 4; ++i)
                bv[i] = *(const float4*)(W1 + (size_t)(lrow + 32 * i) * FEAT + kn + lcol);
        }
        short8 af[2], bfr[4];
#pragma unroll
        for (int t = 0; t < 2; ++t)
            af[t] = *(const short8*)(As + (rh + t * 16 + sub) * LDST + quad * 8);
#pragma unroll
        for (int u = 0; u < 4; ++u)
            bfr[u] = *(const short8*)(Bs + (ch + u * 16 + sub) * LDST + quad * 8);
#pragma unroll
        for (int t = 0; t < 2; ++t)
#pragma unroll
            for (int u = 0; u < 4; ++u)
                acc[t][u] = __builtin_amdgcn_mfma_f32_16x16x32_bf16(af[t], bfr[u], acc[t][u], 0, 0, 0);
        __syncthreads();
    }
    float b1v[4];
#pragma unroll
    for (int u = 0; u < 4; ++u) b1v[u] = b1[ch + u * 16 + sub];
#pragma unroll
    for (int t = 0; t < 2; ++t) {
#pragma unroll
        for (int u = 0; u < 4; ++u) {
            int col = ch + u * 16 + sub;
#pragma unroll
            for (int r2 = 0; r2 < 4; ++r2) {
                int r = rh + t * 16 + quad * 4 + r2;
                int grow = bm + r;
                float v = fmaxf(acc[t][u][r2] + b1v[u], 0.f);
                hs[r][col] = v;
                if (grow < M)
                    h[(size_t)grow * HIDDEN + col] = v;
            }
        }
    }
    __syncthreads();
    // ---- fused prep: wave w preps nodes [w*16, w*16+16) from LDS ----
    {
        const float al0 = attl[2 * lane], al1 = attl[2 * lane + 1];
        const float ab0 = attr[2 * lane], ab1 = attr[2 * lane + 1];
        for (int i = 0; i < 16; ++i) {
            int ln = wave * 16 + i;
            int node = bm + ln;
            if (node >= M) break;
            float2 hv = *(const float2*)(&hs[ln][2 * lane]);
            hbf[(size_t)node * 64 + lane] = pack_bf16(hv.x, hv.y);
            float pl = hv.x * al0 + hv.y * al1;
            float pr = hv.x * ab0 + hv.y * ab1;
            for (int off = 32; off; off >>= 1) {
                pl += __shfl_down(pl, off);
                pr += __shfl_down(pr, off);
            }
            if (lane == 0) {
                al2[node] = make_float2(pl, dis[node]);
                ar_out[node] = pr;
            }
        }
    }
}

// ---------------- aggregate: phase-1 coef batch + packed-FMA hot loop ----------
// hout (f32) written only when non-null: layers 0-2 emit bf16 only (their f32
// output is dead — next layer reads hbf + raw), layer 3 emits f32 only.
__global__ __launch_bounds__(256) void k_aggregate(
                            const unsigned* __restrict__ hbf, const float* __restrict__ raw,
                            const float2* __restrict__ al2, const float* __restrict__ ar,
                            const int* __restrict__ offs, const int* __restrict__ csrc,
                            float* __restrict__ hout, unsigned* __restrict__ houtbf,
                            const float* __restrict__ attl_n, const float* __restrict__ attr_n,
                            float2* __restrict__ al2_o, float* __restrict__ ar_o, int n) {
    int node = (blockIdx.x * blockDim.x + threadIdx.x) >> 6;
    int lane = threadIdx.x & 63;
    if (node >= n) return;
    const int grp = lane >> 4;
    const int sub = lane & 15;
    const float arn = ar[node];
    const float2 selfld = al2[node];
    const float disn = selfld.y;
    f32x2 acc2[4] = {};
    int e0 = offs[node], e1 = offs[node + 1];
    for (int base = e0; base < e1; base += 64) {
        int cnt = min(64, e1 - base);
        // phase 1: one coef per lane (zero-padded past cnt)
        int idx = base + lane;
        int smy = (lane < cnt) ? csrc[idx] : node;
        float2 lmy = al2[smy];
        float cmy = (lane < cnt) ? fast_tanh(lmy.x + arn) * lmy.y * disn : 0.f;
        // phase 2: 16-edge hot loop, src/coef via shfl, packed FMA
        int t = 0;
        for (; t + 16 <= cnt; t += 16) {
            int sa = __shfl(smy, t + grp);
            int sb = __shfl(smy, t + 4 + grp);
            int sc = __shfl(smy, t + 8 + grp);
            int sd = __shfl(smy, t + 12 + grp);
            float ca = __shfl(cmy, t + grp);
            float cb = __shfl(cmy, t + 4 + grp);
            float cc = __shfl(cmy, t + 8 + grp);
            float cd = __shfl(cmy, t + 12 + grp);
            uint4 ra = *(const uint4*)(hbf + (size_t)sa * 64 + sub * 4);
            uint4 rb = *(const uint4*)(hbf + (size_t)sb * 64 + sub * 4);
            uint4 rc = *(const uint4*)(hbf + (size_t)sc * 64 + sub * 4);
            uint4 rd = *(const uint4*)(hbf + (size_t)sd * 64 + sub * 4);
            ACC4P(ca, ra); ACC4P(cb, rb); ACC4P(cc, rc); ACC4P(cd, rd);
        }
        for (; t < cnt; t += 4) {   // zero-padded tail (covers 1-3 leftovers too)
            int sa = __shfl(smy, t + grp);
            float ca = __shfl(cmy, t + grp);
            uint4 ra = *(const uint4*)(hbf + (size_t)sa * 64 + sub * 4);
            ACC4P(ca, ra);
        }
    }
#pragma unroll
    for (int j = 0; j < 4; ++j) {
        acc2[j].x += __shfl_xor(acc2[j].x, 16);
        acc2[j].y += __shfl_xor(acc2[j].y, 16);
        acc2[j].x += __shfl_xor(acc2[j].x, 32);
        acc2[j].y += __shfl_xor(acc2[j].y, 32);
    }
    {   // self-loop term (post-reduce, replicated across groups)
        float c = fast_tanh(selfld.x + arn) * disn * disn;
        uint4 r = *(const uint4*)(hbf + (size_t)node * 64 + sub * 4);
        ACC4P(c, r);
    }
    float o[8];
    {
        float4 rv0 = *(const float4*)(raw + (size_t)node * HIDDEN + sub * 8);
        float4 rv1 = *(const float4*)(raw + (size_t)node * HIDDEN + sub * 8 + 4);
        o[0] = acc2[0].x + 0.3f * rv0.x; o[1] = acc2[0].y + 0.3f * rv0.y;
        o[2] = acc2[1].x + 0.3f * rv0.z; o[3] = acc2[1].y + 0.3f * rv0.w;
        o[4] = acc2[2].x + 0.3f * rv1.x; o[5] = acc2[2].y + 0.3f * rv1.y;
        o[6] = acc2[3].x + 0.3f * rv1.z; o[7] = acc2[3].y + 0.3f * rv1.w;
    }
    if (grp == 0) {
        if (hout) {
            *(float4*)(hout + (size_t)node * HIDDEN + sub * 8) = make_float4(o[0], o[1], o[2], o[3]);
            *(float4*)(hout + (size_t)node * HIDDEN + sub * 8 + 4) = make_float4(o[4], o[5], o[6], o[7]);
        }
        if (houtbf) {
            uint4 pk = make_uint4(pack_bf16(o[0], o[1]), pack_bf16(o[2], o[3]),
                                  pack_bf16(o[4], o[5]), pack_bf16(o[6], o[7]));
            *(uint4*)(houtbf + (size_t)node * 64 + sub * 4) = pk;
        }
    }
    if (attl_n) {
        float4 a0 = *(const float4*)(attl_n + sub * 8);
        float4 a1 = *(const float4*)(attl_n + sub * 8 + 4);
        float4 c0 = *(const float4*)(attr_n + sub * 8);
        float4 c1 = *(const float4*)(attr_n + sub * 8 + 4);
        float pl = o[0] * a0.x + o[1] * a0.y + o[2] * a0.z + o[3] * a0.w +
                   o[4] * a1.x + o[5] * a1.y + o[6] * a1.z + o[7] * a1.w;
        float pr = o[0] * c0.x + o[1] * c0.y + o[2] * c0.z + o[3] * c0.w +
                   o[4] * c1.x + o[5] * c1.y + o[6] * c1.z + o[7] * c1.w;
        for (int off = 8; off; off >>= 1) {
            pl += __shfl_xor(pl, off);
            pr += __shfl_xor(pr, off);
        }
        if (lane == 0) {
            al2_o[node] = make_float2(pl, disn);
            ar_o[node] = pr;
        }
    }
}

// ---------------- output: log_softmax(h @ W2^T + b2) ---------------------------
__global__ __launch_bounds__(256, 4) void k_out(const float* __restrict__ h,
                                                const float* __restrict__ W2,
                                                const float* __restrict__ b2,
                                                float* __restrict__ out, int n) {
    __shared__ float ws[NCLASS * LDSW];
    __shared__ float bs[NCLASS];
    const int tid = threadIdx.x;
    for (int i = tid; i < NCLASS * (HIDDEN / 4); i += 256) {
        int r = i >> 5;          // row (class), 32 float4 per row
        int c4 = i & 31;         // float4 index within row
        *(float4*)(ws + r * LDSW + c4 * 4) = ((const float4*)W2)[i];
    }
    if (tid < NCLASS) bs[tid] = b2[tid];
    __syncthreads();
    int node = blockIdx.x * 32 + (tid >> 3);
    const int ol = tid & 7;
    if (node >= n) return;
    const float* hr = h + (size_t)node * HIDDEN;
    float acc[5];
#pragma unroll
    for (int c = 0; c < 5; ++c) acc[c] = bs[ol + 8 * c];
#pragma unroll
    for (int k0 = 0; k0 < HIDDEN; k0 += 16) {
        float4 h0 = *(const float4*)(hr + k0);
        float4 h1 = *(const float4*)(hr + k0 + 4);
        float4 h2v = *(const float4*)(hr + k0 + 8);
        float4 h3 = *(const float4*)(hr + k0 + 12);
#pragma unroll
        for (int c = 0; c < 5; ++c) {
            const float* w = ws + (ol + 8 * c) * LDSW + k0;
            float4 w0 = *(const float4*)(w);
            float4 w1 = *(const float4*)(w + 4);
            float4 w2v = *(const float4*)(w + 8);
            float4 w3 = *(const float4*)(w + 12);
            acc[c] += h0.x * w0.x + h0.y * w0.y + h0.z * w0.z + h0.w * w0.w +
                      h1.x * w1.x + h1.y * w1.y + h1.z * w1.z + h1.w * w1.w +
                      h2v.x * w2v.x + h2v.y * w2v.y + h2v.z * w2v.z + h2v.w * w2v.w +
                      h3.x * w3.x + h3.y * w3.y + h3.z * w3.z + h3.w * w3.w;
        }
    }
    float m = acc[0];
#pragma unroll
    for (int c = 1; c < 5; ++c) m = fmaxf(m, acc[c]);
    m = fmaxf(m, __shfl_xor(m, 1));
    m = fmaxf(m, __shfl_xor(m, 2));
    m = fmaxf(m, __shfl_xor(m, 4));
    float ssum = 0.f;
#pragma unroll
    for (int c = 0; c < 5; ++c) ssum += expf(acc[c] - m);
    ssum += __shfl_xor(ssum, 1);
    ssum += __shfl_xor(ssum, 2);
    ssum += __shfl_xor(ssum, 4);
    float lse = m + logf(ssum);
    float* orow = out + (size_t)node * NCLASS;
#pragma unroll
    for (int c = 0; c < 5; ++c) orow[ol + 8 * c] = acc[c] - lse;
}

extern "C" void kernel_launch(void* const* d_in, const int* in_sizes, int n_in,
                              void* d_out, int out_size, void* d_ws, size_t ws_size,
                              hipStream_t stream) {
    const float* x    = (const float*)d_in[0];
    const int*   ei   = (const int*)d_in[1];
    const float* W1   = (const float*)d_in[2];
    const float* b1   = (const float*)d_in[3];
    const float* W2   = (const float*)d_in[4];
    const float* b2   = (const float*)d_in[5];
    const float* attl = (const float*)d_in[6];
    const float* attr = (const float*)d_in[7];
    const int N = in_sizes[0] / FEAT;
    const int E = in_sizes[1] / 2;
    float* out = (float*)d_out;

    char* p = (char*)d_ws;
    auto take = [&](size_t bytes) {
        void* q = (void*)p;
        p += (bytes + 255) & ~(size_t)255;
        return q;
    };
    float*    h0   = (float*)take((size_t)N * HIDDEN * 4);  // = raw
    float*    h2   = (float*)take((size_t)N * HIDDEN * 4);  // layer-3 f32 output
    unsigned* hb0  = (unsigned*)take((size_t)N * 64 * 4);
    unsigned* hb1  = (unsigned*)take((size_t)N * 64 * 4);
    int*      deg  = (int*)take((size_t)N * 4);
    float*    dis  = (float*)take((size_t)N * 4);
    int*      offs = (int*)take((size_t)(N + 1) * 4);
    unsigned* partial = (unsigned*)take((size_t)NB * PITCH * 4);
    ushort*   lrank   = (ushort*)take((size_t)E * 2);
    int*      csrc = (int*)take((size_t)E * 4);
    float2*   al2A = (float2*)take((size_t)N * 8);
    float2*   al2B = (float2*)take((size_t)N * 8);
    float*    arA  = (float*)take((size_t)N * 4);
    float*    arB  = (float*)take((size_t)N * 4);
    int*      part = (int*)take(1024);

    const int nbl = (N + 255) / 256;
    const int CE = (E + NB - 1) / NB;

    k_hist<<<NB, 256, 0, stream>>>(ei, E, CE, partial, lrank);
    k_hscan<<<(PITCH + 255) / 256, 256, 0, stream>>>(partial, deg, dis, N);
    k_scan1<<<nbl, 256, 0, stream>>>(deg, offs, part, N);
    k_scan2<<<1, 256, 0, stream>>>(part, nbl);
    k_scan3<<<nbl, 256, 0, stream>>>(offs, part, N, E);
    k_csr_fill<<<NB, 256, 0, stream>>>(ei, E, CE, offs, partial, lrank, csrc);

    k_gemm1p<<<(N + BM1 - 1) / BM1, 256, 0, stream>>>(x, W1, b1, h0, hb0,
                                                      attl, attr, dis, al2A, arA, N);

    unsigned* hbin = hb0, *hbout = hb1;
    float2*   alin = al2A, *alout = al2B;
    float*    arin = arA,  *arout = arB;
    for (int l = 0; l < 4; ++l) {
        const bool last = (l == 3);
        const float* attl_n = (!last) ? (attl + (l + 1) * HIDDEN) : nullptr;
        const float* attr_n = (!last) ? (attr + (l + 1) * HIDDEN) : nullptr;
        float*    fo  = last ? h2 : nullptr;       // f32 out only for final layer
        unsigned* hbo = last ? nullptr : hbout;    // bf16 out only for l<3
        k_aggregate<<<(N + 3) / 4, 256, 0, stream>>>(hbin, h0, alin, arin, offs, csrc,
                                                     fo, hbo, attl_n, attr_n,
                                                     alout, arout, N);
        unsigned* tb = hbin; hbin = hbout; hbout = tb;
        float2* ta = alin; alin = alout; alout = ta;
        float* tr = arin; arin = arout; arout = tr;
    }

    k_out<<<(N + 31) / 32, 256, 0, stream>>>(h2, W2, b2, out, N);
}

// Round 12
// 510.243 us; speedup vs baseline: 1.2667x; 1.0068x over previous
//
#include <hip/hip_runtime.h>
#include <cmath>

// FAGCN: N=50000, E=1.6M, FEAT=512, HIDDEN=128, CLASS=40, 4 layers, eps=0.3
// R21: k_gemm1p restructured for occupancy — BM 64->32 (grid 782->1563,
// 3->6 blocks/CU), acc[2][2]/wave (4 waves x 32-col slices), and the hs LDS
// tile DELETED: prep epilogue runs from registers (bf16 pair via shfl_xor(1);
// att-dots = per-thread partials + 16-lane shfl tree + 1KB pd[] cross-wave
// combine). LDS 48.6KB -> ~14KB. R20 counters: gemm1p 74.7us, occ 21%,
// MfmaUtil 3.3%, VALU 16%, HBM 1.24 TB/s — latency-bound, 3.4x above its
// 22us memory floor, grid-limited at 3.05 blocks/CU. Rest byte-identical.
// Pre-commit: <10us gain => barrier-serialized K-loop is structural; declare
// roofline (aggregate already at random-gather ceiling).

#define HIDDEN 128
#define FEAT 512
#define NCLASS 40
#define LDST 40    // GEMM LDS row stride in ushorts (80 B)
#define LDSW 132   // k_out ws row stride in floats (528 B -> 4-bank shift/row)
#define NB 256     // histogram chunks (= blocks)
#define PITCH 12544  // words per partial row: 4 nodes/word -> supports N<=50176
#define BM1 32     // k_gemm1p M-tile

typedef __attribute__((ext_vector_type(8))) short short8;
typedef __attribute__((ext_vector_type(4))) float f32x4;
typedef __attribute__((ext_vector_type(2))) float f32x2;

__device__ __forceinline__ float bf_lo(unsigned u) { return __uint_as_float(u << 16); }
__device__ __forceinline__ float bf_hi(unsigned u) { return __uint_as_float(u & 0xffff0000u); }
__device__ __forceinline__ f32x2 up2(unsigned u) {
    f32x2 v; v.x = bf_lo(u); v.y = bf_hi(u); return v;
}
__device__ __forceinline__ unsigned pack_bf16(float x, float y) {
    unsigned ux = __float_as_uint(x);
    unsigned uy = __float_as_uint(y);
    unsigned lx = (ux + 0x7fffu + ((ux >> 16) & 1u)) >> 16;
    unsigned hy = (uy + 0x7fffu + ((uy >> 16) & 1u)) & 0xffff0000u;
    return hy | lx;
}
__device__ __forceinline__ float fast_tanh(float x) {
    x = fminf(fmaxf(x, -15.f), 15.f);
    float e = __expf(2.f * x);
    return (e - 1.f) / (e + 1.f);
}

// packed accumulate: 4x v_pk_fma_f32 per uint4
#define ACC4P(c, r) { f32x2 c2; c2.x = c; c2.y = c; \
    acc2[0] = __builtin_elementwise_fma(c2, up2(r.x), acc2[0]); \
    acc2[1] = __builtin_elementwise_fma(c2, up2(r.y), acc2[1]); \
    acc2[2] = __builtin_elementwise_fma(c2, up2(r.z), acc2[2]); \
    acc2[3] = __builtin_elementwise_fma(c2, up2(r.w), acc2[3]); }

// ---------------- per-chunk LDS histogram (8-bit packed) + local rank ----------
__global__ __launch_bounds__(256) void k_hist(const int* __restrict__ ei, int E, int CE,
                                              unsigned* __restrict__ partial,
                                              ushort* __restrict__ lrank) {
    __shared__ unsigned lh[PITCH];
    const int b = blockIdx.x, tid = threadIdx.x;
    for (int w = tid; w < PITCH; w += 256) lh[w] = 0;
    __syncthreads();
    int e0 = b * CE, e1 = min(E, e0 + CE);
    for (int e = e0 + tid; e < e1; e += 256) {
        int dst = ei[E + e];
        int sh = (dst & 3) * 8;
        unsigned old = atomicAdd(&lh[dst >> 2], 1u << sh);
        lrank[e] = (ushort)((old >> sh) & 0xffu);
    }
    __syncthreads();
    unsigned* prow = partial + (size_t)b * PITCH;
    for (int w = tid; w < PITCH; w += 256) prow[w] = lh[w];
}

// ---------------- cross-chunk exclusive scan (in place) + degree + dis ---------
__global__ __launch_bounds__(256) void k_hscan(unsigned* __restrict__ partial,
                                               int* __restrict__ deg,
                                               float* __restrict__ dis, int n) {
    int w = blockIdx.x * 256 + threadIdx.x;
    if (w >= PITCH) return;
    unsigned run = 0;
    size_t idx = w;
    for (int b = 0; b < NB; ++b, idx += PITCH) {
        unsigned v = partial[idx];
        partial[idx] = run;
        run += v;
    }
    int node = 4 * w;
    int d0 = run & 0xffu, d1 = (run >> 8) & 0xffu, d2 = (run >> 16) & 0xffu, d3 = run >> 24;
    if (node < n)     { deg[node]     = d0; dis[node]     = rsqrtf((float)(d0 + 1)); }
    if (node + 1 < n) { deg[node + 1] = d1; dis[node + 1] = rsqrtf((float)(d1 + 1)); }
    if (node + 2 < n) { deg[node + 2] = d2; dis[node + 2] = rsqrtf((float)(d2 + 1)); }
    if (node + 3 < n) { deg[node + 3] = d3; dis[node + 3] = rsqrtf((float)(d3 + 1)); }
}

// ---------------- exclusive scan over node degrees (offs) ----------------
__global__ __launch_bounds__(256) void k_scan1(const int* __restrict__ deg, int* __restrict__ offs,
                                               int* __restrict__ part, int n) {
    __shared__ int s[256];
    int tid = threadIdx.x;
    int gid = blockIdx.x * 256 + tid;
    int v = (gid < n) ? deg[gid] : 0;
    s[tid] = v;
    __syncthreads();
    for (int off = 1; off < 256; off <<= 1) {
        int t = (tid >= off) ? s[tid - off] : 0;
        __syncthreads();
        s[tid] += t;
        __syncthreads();
    }
    if (gid < n) offs[gid] = s[tid] - v;
    if (tid == 255) part[blockIdx.x] = s[255];
}

__global__ __launch_bounds__(256) void k_scan2(int* __restrict__ part, int nb) {
    __shared__ int s[256];
    int tid = threadIdx.x;
    int v = (tid < nb) ? part[tid] : 0;
    s[tid] = v;
    __syncthreads();
    for (int off = 1; off < 256; off <<= 1) {
        int t = (tid >= off) ? s[tid - off] : 0;
        __syncthreads();
        s[tid] += t;
        __syncthreads();
    }
    if (tid < nb) part[tid] = s[tid] - v;
}

__global__ __launch_bounds__(256) void k_scan3(int* __restrict__ offs, const int* __restrict__ part,
                                               int n, int E) {
    int gid = blockIdx.x * 256 + threadIdx.x;
    if (gid < n) offs[gid] += part[blockIdx.x];
    if (gid == 0) offs[n] = E;
}

// ---------------- CSR fill: no atomics; chunk base row staged in LDS -----------
__global__ __launch_bounds__(256) void k_csr_fill(const int* __restrict__ ei, int E, int CE,
                                                  const int* __restrict__ offs,
                                                  const unsigned* __restrict__ partial,
                                                  const ushort* __restrict__ lrank,
                                                  int* __restrict__ csrc) {
    __shared__ unsigned lp[PITCH];
    const int b = blockIdx.x, tid = threadIdx.x;
    const unsigned* prow = partial + (size_t)b * PITCH;
    for (int w = tid; w < PITCH; w += 256) lp[w] = prow[w];
    __syncthreads();
    int e0 = b * CE, e1 = min(E, e0 + CE);
    for (int e = e0 + tid; e < e1; e += 256) {
        int dst = ei[E + e];
        int src = ei[e];
        unsigned wv = lp[dst >> 2];
        int base = (wv >> ((dst & 3) * 8)) & 0xffu;
        csrc[offs[dst] + base + (int)lrank[e]] = src;
    }
}

// ---------------- GEMM1 + register-epilogue prep (BM=32, 4 col-slice waves) ----
// wave w: cols [w*32, w*32+32), rows [0,32). Thread frag: rows t*16+quad*4+r2
// (t<2, r2<4), cols ch+u*16+sub (u<2). Epilogue: h write from regs; hbf via
// shfl_xor(1) pairing (lane l / l^1 hold same rows, adjacent cols); att-dots
// via per-thread partials + 16-lane shfl tree + pd[] cross-wave combine.
__global__ __launch_bounds__(256) void k_gemm1p(const float* __restrict__ x,
                                                const float* __restrict__ W1,
                                                const float* __restrict__ b1,
                                                float* __restrict__ h,
                                                unsigned* __restrict__ hbf,
                                                const float* __restrict__ attl,
                                                const float* __restrict__ attr,
                                                const float* __restrict__ dis,
                                                float2* __restrict__ al2,
                                                float* __restrict__ ar_out, int M) {
    __shared__ ushort As[BM1 * LDST];          // 2.5 KB
    __shared__ ushort Bs[128 * LDST];          // 10 KB
    __shared__ float pd[4][BM1][2];            // 1 KB: per-wave partial dots
    const int tid = threadIdx.x;
    const int bm = blockIdx.x * BM1;
    const int wave = tid >> 6, lane = tid & 63;
    const int ch = wave * 32;                  // wave col offset: 0/32/64/96
    const int sub = lane & 15, quad = lane >> 4;
    const int lrow = tid >> 3;                 // 0..31
    const int lcol = (tid & 7) * 4;            // 0..28
    f32x4 acc[2][2] = {};
    float4 av, bv[4];
    // prologue: load K-tile 0 into registers
    {
        int grow = bm + lrow;
        av = (grow < M) ? *(const float4*)(x + (size_t)grow * FEAT + lcol)
                        : make_float4(0.f, 0.f, 0.f, 0.f);
#pragma unroll
        for (int i = 0; i < 4; ++i)
            bv[i] = *(const float4*)(W1 + (size_t)(lrow + 32 * i) * FEAT + lcol);
    }
    for (int k0 = 0; k0 < FEAT; k0 += 32) {
        *(uint2*)(As + lrow * LDST + lcol) =
            make_uint2(pack_bf16(av.x, av.y), pack_bf16(av.z, av.w));
#pragma unroll
        for (int i = 0; i < 4; ++i)
            *(uint2*)(Bs + (lrow + 32 * i) * LDST + lcol) =
                make_uint2(pack_bf16(bv[i].x, bv[i].y), pack_bf16(bv[i].z, bv[i].w));
        __syncthreads();
        if (k0 + 32 < FEAT) {
            const int kn = k0 + 32;
            int grow = bm + lrow;
            av = (grow < M) ? *(const float4*)(x + (size_t)grow * FEAT + kn + lcol)
                            : make_float4(0.f, 0.f, 0.f, 0.f);
#pragma unroll
            for (int i = 0; i < 4; ++i)
                bv[i] = *(const float4*)(W1 + (size_t)(lrow + 32 * i) * FEAT + kn + lcol);
        }
        short8 af[2], bfr[2];
#pragma unroll
        for (int t = 0; t < 2; ++t)
            af[t] = *(const short8*)(As + (t * 16 + sub) * LDST + quad * 8);
#pragma unroll
        for (int u = 0; u < 2; ++u)
            bfr[u] = *(const short8*)(Bs + (ch + u * 16 + sub) * LDST + quad * 8);
#pragma unroll
        for (int t = 0; t < 2; ++t)
#pragma unroll
            for (int u = 0; u < 2; ++u)
                acc[t][u] = __builtin_amdgcn_mfma_f32_16x16x32_bf16(af[t], bfr[u], acc[t][u], 0, 0, 0);
        __syncthreads();
    }
    // ---- epilogue: relu + h write from registers ----
    float b1v[2];
#pragma unroll
    for (int u = 0; u < 2; ++u) b1v[u] = b1[ch + u * 16 + sub];
    float v[2][2][4];
#pragma unroll
    for (int t = 0; t < 2; ++t)
#pragma unroll
        for (int u = 0; u < 2; ++u)
#pragma unroll
            for (int r2 = 0; r2 < 4; ++r2) {
                int r = t * 16 + quad * 4 + r2;
                int grow = bm + r;
                float vv = fmaxf(acc[t][u][r2] + b1v[u], 0.f);
                v[t][u][r2] = vv;
                if (grow < M)
                    h[(size_t)grow * HIDDEN + ch + u * 16 + sub] = vv;
            }
    // ---- hbf: bf16 pair with lane^1 (same rows, adjacent col) ----
#pragma unroll
    for (int t = 0; t < 2; ++t)
#pragma unroll
        for (int u = 0; u < 2; ++u)
#pragma unroll
            for (int r2 = 0; r2 < 4; ++r2) {
                float vp = __shfl_xor(v[t][u][r2], 1);
                if (!(lane & 1)) {
                    int node = bm + t * 16 + quad * 4 + r2;
                    if (node < M) {
                        unsigned pk = pack_bf16(v[t][u][r2], vp);
                        hbf[(size_t)node * 64 + ((ch + u * 16 + sub) >> 1)] = pk;
                    }
                }
            }
    // ---- att dots: per-thread partials -> 16-lane tree -> cross-wave LDS ----
    float alc[2], arc[2];
#pragma unroll
    for (int u = 0; u < 2; ++u) {
        alc[u] = attl[ch + u * 16 + sub];
        arc[u] = attr[ch + u * 16 + sub];
    }
#pragma unroll
    for (int t = 0; t < 2; ++t)
#pragma unroll
        for (int r2 = 0; r2 < 4; ++r2) {
            float pl = v[t][0][r2] * alc[0] + v[t][1][r2] * alc[1];
            float pr = v[t][0][r2] * arc[0] + v[t][1][r2] * arc[1];
            pl += __shfl_xor(pl, 1); pl += __shfl_xor(pl, 2);
            pl += __shfl_xor(pl, 4); pl += __shfl_xor(pl, 8);
            pr += __shfl_xor(pr, 1); pr += __shfl_xor(pr, 2);
            pr += __shfl_xor(pr, 4); pr += __shfl_xor(pr, 8);
            if (sub == 0) {
                int r = t * 16 + quad * 4 + r2;
                pd[wave][r][0] = pl;
                pd[wave][r][1] = pr;
            }
        }
    __syncthreads();
    if (tid < BM1) {
        int node = bm + tid;
        if (node < M) {
            float pl = pd[0][tid][0] + pd[1][tid][0] + pd[2][tid][0] + pd[3][tid][0];
            float pr = pd[0][tid][1] + pd[1][tid][1] + pd[2][tid][1] + pd[3][tid][1];
            al2[node] = make_float2(pl, dis[node]);
            ar_out[node] = pr;
        }
    }
}

// ---------------- aggregate: phase-1 coef batch + packed-FMA hot loop ----------
// hout (f32) written only when non-null: layers 0-2 emit bf16 only (their f32
// output is dead — next layer reads hbf + raw), layer 3 emits f32 only.
__global__ __launch_bounds__(256) void k_aggregate(
                            const unsigned* __restrict__ hbf, const float* __restrict__ raw,
                            const float2* __restrict__ al2, const float* __restrict__ ar,
                            const int* __restrict__ offs, const int* __restrict__ csrc,
                            float* __restrict__ hout, unsigned* __restrict__ houtbf,
                            const float* __restrict__ attl_n, const float* __restrict__ attr_n,
                            float2* __restrict__ al2_o, float* __restrict__ ar_o, int n) {
    int node = (blockIdx.x * blockDim.x + threadIdx.x) >> 6;
    int lane = threadIdx.x & 63;
    if (node >= n) return;
    const int grp = lane >> 4;
    const int sub = lane & 15;
    const float arn = ar[node];
    const float2 selfld = al2[node];
    const float disn = selfld.y;
    f32x2 acc2[4] = {};
    int e0 = offs[node], e1 = offs[node + 1];
    for (int base = e0; base < e1; base += 64) {
        int cnt = min(64, e1 - base);
        // phase 1: one coef per lane (zero-padded past cnt)
        int idx = base + lane;
        int smy = (lane < cnt) ? csrc[idx] : node;
        float2 lmy = al2[smy];
        float cmy = (lane < cnt) ? fast_tanh(lmy.x + arn) * lmy.y * disn : 0.f;
        // phase 2: 16-edge hot loop, src/coef via shfl, packed FMA
        int t = 0;
        for (; t + 16 <= cnt; t += 16) {
            int sa = __shfl(smy, t + grp);
            int sb = __shfl(smy, t + 4 + grp);
            int sc = __shfl(smy, t + 8 + grp);
            int sd = __shfl(smy, t + 12 + grp);
            float ca = __shfl(cmy, t + grp);
            float cb = __shfl(cmy, t + 4 + grp);
            float cc = __shfl(cmy, t + 8 + grp);
            float cd = __shfl(cmy, t + 12 + grp);
            uint4 ra = *(const uint4*)(hbf + (size_t)sa * 64 + sub * 4);
            uint4 rb = *(const uint4*)(hbf + (size_t)sb * 64 + sub * 4);
            uint4 rc = *(const uint4*)(hbf + (size_t)sc * 64 + sub * 4);
            uint4 rd = *(const uint4*)(hbf + (size_t)sd * 64 + sub * 4);
            ACC4P(ca, ra); ACC4P(cb, rb); ACC4P(cc, rc); ACC4P(cd, rd);
        }
        for (; t < cnt; t += 4) {   // zero-padded tail (covers 1-3 leftovers too)
            int sa = __shfl(smy, t + grp);
            float ca = __shfl(cmy, t + grp);
            uint4 ra = *(const uint4*)(hbf + (size_t)sa * 64 + sub * 4);
            ACC4P(ca, ra);
        }
    }
#pragma unroll
    for (int j = 0; j < 4; ++j) {
        acc2[j].x += __shfl_xor(acc2[j].x, 16);
        acc2[j].y += __shfl_xor(acc2[j].y, 16);
        acc2[j].x += __shfl_xor(acc2[j].x, 32);
        acc2[j].y += __shfl_xor(acc2[j].y, 32);
    }
    {   // self-loop term (post-reduce, replicated across groups)
        float c = fast_tanh(selfld.x + arn) * disn * disn;
        uint4 r = *(const uint4*)(hbf + (size_t)node * 64 + sub * 4);
        ACC4P(c, r);
    }
    float o[8];
    {
        float4 rv0 = *(const float4*)(raw + (size_t)node * HIDDEN + sub * 8);
        float4 rv1 = *(const float4*)(raw + (size_t)node * HIDDEN + sub * 8 + 4);
        o[0] = acc2[0].x + 0.3f * rv0.x; o[1] = acc2[0].y + 0.3f * rv0.y;
        o[2] = acc2[1].x + 0.3f * rv0.z; o[3] = acc2[1].y + 0.3f * rv0.w;
        o[4] = acc2[2].x + 0.3f * rv1.x; o[5] = acc2[2].y + 0.3f * rv1.y;
        o[6] = acc2[3].x + 0.3f * rv1.z; o[7] = acc2[3].y + 0.3f * rv1.w;
    }
    if (grp == 0) {
        if (hout) {
            *(float4*)(hout + (size_t)node * HIDDEN + sub * 8) = make_float4(o[0], o[1], o[2], o[3]);
            *(float4*)(hout + (size_t)node * HIDDEN + sub * 8 + 4) = make_float4(o[4], o[5], o[6], o[7]);
        }
        if (houtbf) {
            uint4 pk = make_uint4(pack_bf16(o[0], o[1]), pack_bf16(o[2], o[3]),
                                  pack_bf16(o[4], o[5]), pack_bf16(o[6], o[7]));
            *(uint4*)(houtbf + (size_t)node * 64 + sub * 4) = pk;
        }
    }
    if (attl_n) {
        float4 a0 = *(const float4*)(attl_n + sub * 8);
        float4 a1 = *(const float4*)(attl_n + sub * 8 + 4);
        float4 c0 = *(const float4*)(attr_n + sub * 8);
        float4 c1 = *(const float4*)(attr_n + sub * 8 + 4);
        float pl = o[0] * a0.x + o[1] * a0.y + o[2] * a0.z + o[3] * a0.w +
                   o[4] * a1.x + o[5] * a1.y + o[6] * a1.z + o[7] * a1.w;
        float pr = o[0] * c0.x + o[1] * c0.y + o[2] * c0.z + o[3] * c0.w +
                   o[4] * c1.x + o[5] * c1.y + o[6] * c1.z + o[7] * c1.w;
        for (int off = 8; off; off >>= 1) {
            pl += __shfl_xor(pl, off);
            pr += __shfl_xor(pr, off);
        }
        if (lane == 0) {
            al2_o[node] = make_float2(pl, disn);
            ar_o[node] = pr;
        }
    }
}

// ---------------- output: log_softmax(h @ W2^T + b2) ---------------------------
__global__ __launch_bounds__(256, 4) void k_out(const float* __restrict__ h,
                                                const float* __restrict__ W2,
                                                const float* __restrict__ b2,
                                                float* __restrict__ out, int n) {
    __shared__ float ws[NCLASS * LDSW];
    __shared__ float bs[NCLASS];
    const int tid = threadIdx.x;
    for (int i = tid; i < NCLASS * (HIDDEN / 4); i += 256) {
        int r = i >> 5;          // row (class), 32 float4 per row
        int c4 = i & 31;         // float4 index within row
        *(float4*)(ws + r * LDSW + c4 * 4) = ((const float4*)W2)[i];
    }
    if (tid < NCLASS) bs[tid] = b2[tid];
    __syncthreads();
    int node = blockIdx.x * 32 + (tid >> 3);
    const int ol = tid & 7;
    if (node >= n) return;
    const float* hr = h + (size_t)node * HIDDEN;
    float acc[5];
#pragma unroll
    for (int c = 0; c < 5; ++c) acc[c] = bs[ol + 8 * c];
#pragma unroll
    for (int k0 = 0; k0 < HIDDEN; k0 += 16) {
        float4 h0 = *(const float4*)(hr + k0);
        float4 h1 = *(const float4*)(hr + k0 + 4);
        float4 h2v = *(const float4*)(hr + k0 + 8);
        float4 h3 = *(const float4*)(hr + k0 + 12);
#pragma unroll
        for (int c = 0; c < 5; ++c) {
            const float* w = ws + (ol + 8 * c) * LDSW + k0;
            float4 w0 = *(const float4*)(w);
            float4 w1 = *(const float4*)(w + 4);
            float4 w2v = *(const float4*)(w + 8);
            float4 w3 = *(const float4*)(w + 12);
            acc[c] += h0.x * w0.x + h0.y * w0.y + h0.z * w0.z + h0.w * w0.w +
                      h1.x * w1.x + h1.y * w1.y + h1.z * w1.z + h1.w * w1.w +
                      h2v.x * w2v.x + h2v.y * w2v.y + h2v.z * w2v.z + h2v.w * w2v.w +
                      h3.x * w3.x + h3.y * w3.y + h3.z * w3.z + h3.w * w3.w;
        }
    }
    float m = acc[0];
#pragma unroll
    for (int c = 1; c < 5; ++c) m = fmaxf(m, acc[c]);
    m = fmaxf(m, __shfl_xor(m, 1));
    m = fmaxf(m, __shfl_xor(m, 2));
    m = fmaxf(m, __shfl_xor(m, 4));
    float ssum = 0.f;
#pragma unroll
    for (int c = 0; c < 5; ++c) ssum += expf(acc[c] - m);
    ssum += __shfl_xor(ssum, 1);
    ssum += __shfl_xor(ssum, 2);
    ssum += __shfl_xor(ssum, 4);
    float lse = m + logf(ssum);
    float* orow = out + (size_t)node * NCLASS;
#pragma unroll
    for (int c = 0; c < 5; ++c) orow[ol + 8 * c] = acc[c] - lse;
}

extern "C" void kernel_launch(void* const* d_in, const int* in_sizes, int n_in,
                              void* d_out, int out_size, void* d_ws, size_t ws_size,
                              hipStream_t stream) {
    const float* x    = (const float*)d_in[0];
    const int*   ei   = (const int*)d_in[1];
    const float* W1   = (const float*)d_in[2];
    const float* b1   = (const float*)d_in[3];
    const float* W2   = (const float*)d_in[4];
    const float* b2   = (const float*)d_in[5];
    const float* attl = (const float*)d_in[6];
    const float* attr = (const float*)d_in[7];
    const int N = in_sizes[0] / FEAT;
    const int E = in_sizes[1] / 2;
    float* out = (float*)d_out;

    char* p = (char*)d_ws;
    auto take = [&](size_t bytes) {
        void* q = (void*)p;
        p += (bytes + 255) & ~(size_t)255;
        return q;
    };
    float*    h0   = (float*)take((size_t)N * HIDDEN * 4);  // = raw
    float*    h2   = (float*)take((size_t)N * HIDDEN * 4);  // layer-3 f32 output
    unsigned* hb0  = (unsigned*)take((size_t)N * 64 * 4);
    unsigned* hb1  = (unsigned*)take((size_t)N * 64 * 4);
    int*      deg  = (int*)take((size_t)N * 4);
    float*    dis  = (float*)take((size_t)N * 4);
    int*      offs = (int*)take((size_t)(N + 1) * 4);
    unsigned* partial = (unsigned*)take((size_t)NB * PITCH * 4);
    ushort*   lrank   = (ushort*)take((size_t)E * 2);
    int*      csrc = (int*)take((size_t)E * 4);
    float2*   al2A = (float2*)take((size_t)N * 8);
    float2*   al2B = (float2*)take((size_t)N * 8);
    float*    arA  = (float*)take((size_t)N * 4);
    float*    arB  = (float*)take((size_t)N * 4);
    int*      part = (int*)take(1024);

    const int nbl = (N + 255) / 256;
    const int CE = (E + NB - 1) / NB;

    k_hist<<<NB, 256, 0, stream>>>(ei, E, CE, partial, lrank);
    k_hscan<<<(PITCH + 255) / 256, 256, 0, stream>>>(partial, deg, dis, N);
    k_scan1<<<nbl, 256, 0, stream>>>(deg, offs, part, N);
    k_scan2<<<1, 256, 0, stream>>>(part, nbl);
    k_scan3<<<nbl, 256, 0, stream>>>(offs, part, N, E);
    k_csr_fill<<<NB, 256, 0, stream>>>(ei, E, CE, offs, partial, lrank, csrc);

    k_gemm1p<<<(N + BM1 - 1) / BM1, 256, 0, stream>>>(x, W1, b1, h0, hb0,
                                                      attl, attr, dis, al2A, arA, N);

    unsigned* hbin = hb0, *hbout = hb1;
    float2*   alin = al2A, *alout = al2B;
    float*    arin = arA,  *arout = arB;
    for (int l = 0; l < 4; ++l) {
        const bool last = (l == 3);
        const float* attl_n = (!last) ? (attl + (l + 1) * HIDDEN) : nullptr;
        const float* attr_n = (!last) ? (attr + (l + 1) * HIDDEN) : nullptr;
        float*    fo  = last ? h2 : nullptr;       // f32 out only for final layer
        unsigned* hbo = last ? nullptr : hbout;    // bf16 out only for l<3
        k_aggregate<<<(N + 3) / 4, 256, 0, stream>>>(hbin, h0, alin, arin, offs, csrc,
                                                     fo, hbo, attl_n, attr_n,
                                                     alout, arout, N);
        unsigned* tb = hbin; hbin = hbout; hbout = tb;
        float2* ta = alin; alin = alout; alout = ta;
        float* tr = arin; arin = arout; arout = tr;
    }

    k_out<<<(N + 31) / 32, 256, 0, stream>>>(h2, W2, b2, out, N);
}